// Round 2
// baseline (1438.427 us; speedup 1.0000x reference)
//
#include <hip/hip_runtime.h>
#include <hip/hip_bf16.h>
#include <stdint.h>

typedef __hip_bfloat16 bf16;
typedef unsigned int u32;
typedef __attribute__((ext_vector_type(8))) short short8;
typedef __attribute__((ext_vector_type(4))) float f32x4;

#define NNODES 30000
#define NEDGES 300000
#define NODE_PAD 30080   // 235*128
#define EDGE_PAD 300032  // 2344*128
#define NEG_SLOPE 0.2f
#define BN_EPS 1e-5f

__device__ __forceinline__ float b2f(short s) {
  u32 u = ((u32)(unsigned short)s) << 16;
  return __uint_as_float(u);
}
__device__ __forceinline__ short f2b(float f) {
  bf16 h = __float2bfloat16(f);
  return *(short*)&h;
}

__device__ __forceinline__ void gload16(const void* g, void* l) {
  __builtin_amdgcn_global_load_lds(
      (__attribute__((address_space(1))) unsigned int*)(uintptr_t)g,
      (__attribute__((address_space(3))) unsigned int*)(uintptr_t)l, 16, 0, 0);
}

// ---------------- tiny utility kernels ----------------

__global__ void zfill(u32* __restrict__ p, int n) {
  int i = blockIdx.x * 256 + threadIdx.x;
  if (i < n) p[i] = 0u;
}

__global__ void fillpat(u32* __restrict__ p, u32 v, int n) {
  int i = blockIdx.x * 256 + threadIdx.x;
  if (i < n) p[i] = v;
}

// fp32 -> bf16 with row padding (rows >= rows_valid write 0)
__global__ void cvt_bf16_pad(const float* __restrict__ src, bf16* __restrict__ dst,
                             int rows_valid, int total, int cols) {
  int i = blockIdx.x * 256 + threadIdx.x;
  if (i >= total) return;
  int r = i / cols;
  float v = (r < rows_valid) ? src[i] : 0.f;
  dst[i] = __float2bfloat16(v);
}

// w45[n][k] = n<256 ? w4[n][k] : w4[n-256][128+k]   (n in [0,512), k in [0,128))
__global__ void cvt_w45(const float* __restrict__ w4, bf16* __restrict__ w45b) {
  int i = blockIdx.x * 256 + threadIdx.x;
  if (i >= 512 * 128) return;
  int n = i >> 7, k = i & 127;
  float v = (n < 256) ? w4[n * 256 + k] : w4[(n - 256) * 256 + 128 + k];
  w45b[i] = __float2bfloat16(v);
}

// ---------------- GEMM: C[M,N] = A[M,K] @ B[N,K]^T  (bf16 in) ----------------
// 128x128 tile, BK=64, 4 waves (2x2), wave = 4x4 frags of 16x16x32 MFMA.
// XOR swizzle: LDS cell (row, c8) holds global (row, c8^(row&7)); applied on the
// pre-swizzled global source (linear LDS dest for global_load_lds) and on ds_read.
template <bool BF16OUT>
__global__ __launch_bounds__(256) void gemm_bt(
    const bf16* __restrict__ A, const bf16* __restrict__ B, void* __restrict__ Cout,
    int K, int ldc, int Mvalid, int Nvalid, const float* __restrict__ bias) {
  __shared__ __align__(16) short sm[2][128 * 64];
  const int tid = threadIdx.x;
  const int lane = tid & 63;
  const int wid = tid >> 6;
  const int wr = wid >> 1, wc = wid & 1;
  const size_t arow0 = (size_t)blockIdx.x * 128;
  const size_t brow0 = (size_t)blockIdx.y * 128;
  f32x4 acc[4][4] = {};
  const int nk = K >> 6;
  for (int kt = 0; kt < nk; ++kt) {
    const int kbase = kt * 64;
#pragma unroll
    for (int i = 0; i < 4; ++i) {
      int s = i * 256 + tid;
      int row = s >> 3;
      int c8l = (s & 7) ^ (row & 7);
      gload16(A + (arow0 + row) * K + kbase + c8l * 8, &sm[0][s * 8]);
      gload16(B + (brow0 + row) * K + kbase + c8l * 8, &sm[1][s * 8]);
    }
    __syncthreads();
#pragma unroll
    for (int ks = 0; ks < 2; ++ks) {
      short8 af[4], bfr[4];
      const int cg = ks * 4 + (lane >> 4);
#pragma unroll
      for (int m = 0; m < 4; ++m) {
        int row = wr * 64 + m * 16 + (lane & 15);
        af[m] = *(const short8*)&sm[0][row * 64 + ((cg ^ (row & 7)) << 3)];
      }
#pragma unroll
      for (int n = 0; n < 4; ++n) {
        int row = wc * 64 + n * 16 + (lane & 15);
        bfr[n] = *(const short8*)&sm[1][row * 64 + ((cg ^ (row & 7)) << 3)];
      }
#pragma unroll
      for (int m = 0; m < 4; ++m)
#pragma unroll
        for (int n = 0; n < 4; ++n)
          acc[m][n] = __builtin_amdgcn_mfma_f32_16x16x32_bf16(af[m], bfr[n], acc[m][n], 0, 0, 0);
    }
    __syncthreads();
  }
  const int rbase = (int)arow0 + wr * 64 + (lane >> 4) * 4;
  const int cbase = (int)brow0 + wc * 64 + (lane & 15);
#pragma unroll
  for (int m = 0; m < 4; ++m) {
#pragma unroll
    for (int n = 0; n < 4; ++n) {
      int col = cbase + n * 16;
      if (col >= Nvalid) continue;
      float badd = bias ? bias[col] : 0.f;
#pragma unroll
      for (int r = 0; r < 4; ++r) {
        int row = rbase + m * 16 + r;
        if (row < Mvalid) {
          if constexpr (BF16OUT)
            ((bf16*)Cout)[(size_t)row * ldc + col] = __float2bfloat16(acc[m][n][r] + badd);
          else
            ((float*)Cout)[(size_t)row * ldc + col] = acc[m][n][r] + badd;
        }
      }
    }
  }
}

// ---------------- GAT pieces ----------------

__global__ __launch_bounds__(256) void att_reduce(
    const float* __restrict__ h, const float* __restrict__ ats, const float* __restrict__ atd,
    float* __restrict__ a_s, float* __restrict__ a_d) {
  int n = blockIdx.x;
  int lane = threadIdx.x & 63;
  int hd = threadIdx.x >> 6;
  const float* hp = h + (size_t)n * 512 + hd * 128;
  const float* sw = ats + hd * 128;
  const float* dw = atd + hd * 128;
  float h1 = hp[lane], h2 = hp[lane + 64];
  float s = h1 * sw[lane] + h2 * sw[lane + 64];
  float d = h1 * dw[lane] + h2 * dw[lane + 64];
#pragma unroll
  for (int off = 32; off > 0; off >>= 1) {
    s += __shfl_down(s, off);
    d += __shfl_down(d, off);
  }
  if (lane == 0) {
    a_s[n * 4 + hd] = s;
    a_d[n * 4 + hd] = d;
  }
}

__global__ void edge_alpha_max(const int* __restrict__ ei, const float* __restrict__ a_s,
                               const float* __restrict__ a_d, float* __restrict__ alphaE,
                               u32* __restrict__ amaxU) {
  int t = blockIdx.x * 256 + threadIdx.x;
  if (t >= NEDGES * 4) return;
  int e = t >> 2, h = t & 3;
  int s = ei[e], d = ei[NEDGES + e];
  float a = a_s[s * 4 + h] + a_d[d * 4 + h];
  a = (a > 0.f) ? a : NEG_SLOPE * a;
  alphaE[t] = a;
  u32 bits = __float_as_uint(a);
  u32 key = bits ^ (((int)bits < 0) ? 0xFFFFFFFFu : 0x80000000u);
  atomicMax(&amaxU[d * 4 + h], key);
}

__global__ void edge_exp_sum(const int* __restrict__ ei, float* __restrict__ alphaE,
                             const u32* __restrict__ amaxU, float* __restrict__ denom) {
  int t = blockIdx.x * 256 + threadIdx.x;
  if (t >= NEDGES * 4) return;
  int e = t >> 2, h = t & 3;
  int d = ei[NEDGES + e];
  u32 k = amaxU[d * 4 + h];
  u32 bits = (k & 0x80000000u) ? (k ^ 0x80000000u) : ~k;
  float am = __uint_as_float(bits);
  float ev = __expf(alphaE[t] - am);
  alphaE[t] = ev;
  atomicAdd(&denom[d * 4 + h], ev);
}

// agg[dst,d] += sum_h h[src, h*128+d]*coef_h/4 ; 2 edges per 256-thr block
__global__ void edge_scatter(const int* __restrict__ ei, const float* __restrict__ hbuf,
                             const float* __restrict__ evals, const float* __restrict__ denom,
                             float* __restrict__ agg) {
  int e = blockIdx.x * 2 + (threadIdx.x >> 7);
  int d = threadIdx.x & 127;
  int s = ei[e], dd = ei[NEDGES + e];
  float sum = 0.f;
#pragma unroll
  for (int h = 0; h < 4; ++h) {
    float coef = evals[e * 4 + h] / denom[dd * 4 + h];
    sum += hbuf[(size_t)s * 512 + h * 128 + d] * coef;
  }
  atomicAdd(&agg[dd * 128 + d], sum * 0.25f);
}

// ---------------- BatchNorm pieces ----------------

__global__ void col_stats(const float* __restrict__ X, float* __restrict__ stats,
                          int rows, int cols, int rpb) {
  int c = threadIdx.x;
  int r0 = blockIdx.x * rpb;
  int r1 = r0 + rpb;
  if (r1 > rows) r1 = rows;
  float s = 0.f, q = 0.f;
  for (int r = r0; r < r1; ++r) {
    float v = X[(size_t)r * cols + c];
    s += v;
    q += v * v;
  }
  atomicAdd(&stats[c], s);
  atomicAdd(&stats[cols + c], q);
}

__global__ void col_stats_bf16(const bf16* __restrict__ X, float* __restrict__ stats,
                               int rows, int cols, int rpb) {
  int c = threadIdx.x;
  int r0 = blockIdx.x * rpb;
  int r1 = r0 + rpb;
  if (r1 > rows) r1 = rows;
  float s = 0.f, q = 0.f;
  for (int r = r0; r < r1; ++r) {
    float v = __bfloat162float(X[(size_t)r * cols + c]);
    s += v;
    q += v * v;
  }
  atomicAdd(&stats[c], s);
  atomicAdd(&stats[cols + c], q);
}

__global__ void bn_relu_node(const float* __restrict__ agg, const float* __restrict__ stats,
                             const float* __restrict__ w, const float* __restrict__ b,
                             bf16* __restrict__ xout) {
  int i = blockIdx.x * 256 + threadIdx.x;
  if (i >= NODE_PAD * 128) return;
  int r = i >> 7, c = i & 127;
  float v = 0.f;
  if (r < NNODES) {
    float m = stats[c] * (1.f / NNODES);
    float var = stats[128 + c] * (1.f / NNODES) - m * m;
    float rstd = rsqrtf(var + BN_EPS);
    v = fmaxf((agg[i] - m) * rstd * w[c] + b[c], 0.f);
  }
  xout[i] = __float2bfloat16(v);
}

__global__ void bn_res_relu_node(const float* __restrict__ agg, const float* __restrict__ stats,
                                 const float* __restrict__ w, const float* __restrict__ b,
                                 const bf16* __restrict__ x1b, bf16* __restrict__ xrb) {
  int i = blockIdx.x * 256 + threadIdx.x;
  if (i >= NODE_PAD * 128) return;
  int r = i >> 7, c = i & 127;
  float v = 0.f;
  if (r < NNODES) {
    float m = stats[c] * (1.f / NNODES);
    float var = stats[128 + c] * (1.f / NNODES) - m * m;
    float rstd = rsqrtf(var + BN_EPS);
    v = fmaxf((agg[i] - m) * rstd * w[c] + b[c] + __bfloat162float(x1b[i]), 0.f);
  }
  xrb[i] = __float2bfloat16(v);
}

// ---------------- edge-MLP pieces (y1 = P[src] + Q[dst], never materialized) --

// column stats of y1 over edges: thread=col, block=chunk of edges
__global__ void e_stats(const int* __restrict__ ei, const float* __restrict__ PQ,
                        float* __restrict__ stats) {
  int c = threadIdx.x;  // 256
  int r0 = blockIdx.x * 512;
  int r1 = r0 + 512;
  if (r1 > NEDGES) r1 = NEDGES;
  float s = 0.f, q = 0.f;
  for (int e = r0; e < r1; ++e) {
    int sn = ei[e], dn = ei[NEDGES + e];
    float v = PQ[(size_t)sn * 512 + c] + PQ[(size_t)dn * 512 + 256 + c];
    s += v;
    q += v * v;
  }
  atomicAdd(&stats[c], s);
  atomicAdd(&stats[256 + c], q);
}

// ef2[e,c] = relu(bn3(P[src]+Q[dst]) + ef1[e,c]),  ef1 gathered from xr
__global__ void build_ef2(const int* __restrict__ ei, const float* __restrict__ PQ,
                          const bf16* __restrict__ xrb, const float* __restrict__ stats,
                          const float* __restrict__ w, const float* __restrict__ b,
                          bf16* __restrict__ ef2) {
  int e = blockIdx.x, c = threadIdx.x;
  float out = 0.f;
  if (e < NEDGES) {
    int sn = ei[e], dn = ei[NEDGES + e];
    float v = PQ[(size_t)sn * 512 + c] + PQ[(size_t)dn * 512 + 256 + c];
    float m = stats[c] * (1.f / NEDGES);
    float var = stats[256 + c] * (1.f / NEDGES) - m * m;
    float rstd = rsqrtf(var + BN_EPS);
    float res = __bfloat162float(xrb[(size_t)(c < 128 ? sn : dn) * 128 + (c & 127)]);
    out = fmaxf((v - m) * rstd * w[c] + b[c] + res, 0.f);
  }
  ef2[(size_t)e * 256 + c] = __float2bfloat16(out);
}

// y2 <- relu(bn4(y2) + ef2), in place, 8 elems/thread
__global__ void ef3_inplace(bf16* __restrict__ y2, const bf16* __restrict__ ef2,
                            const float* __restrict__ stats, const float* __restrict__ w,
                            const float* __restrict__ b) {
  int t = blockIdx.x * 256 + threadIdx.x;  // NEDGES*32 threads exactly
  size_t base = (size_t)t * 8;
  int c0 = (int)(base & 255);
  short8 yv = *(const short8*)(y2 + base);
  short8 ev = *(const short8*)(ef2 + base);
  short8 out;
#pragma unroll
  for (int j = 0; j < 8; ++j) {
    int c = c0 + j;
    float m = stats[c] * (1.f / NEDGES);
    float var = stats[256 + c] * (1.f / NEDGES) - m * m;
    float rstd = rsqrtf(var + BN_EPS);
    float v = fmaxf((b2f(yv[j]) - m) * rstd * w[c] + b[c] + b2f(ev[j]), 0.f);
    out[j] = f2b(v);
  }
  *(short8*)(y2 + base) = out;
}

// ---------------- launch ----------------

extern "C" void kernel_launch(void* const* d_in, const int* in_sizes, int n_in,
                              void* d_out, int out_size, void* d_ws, size_t ws_size,
                              hipStream_t stream) {
  const float* x    = (const float*)d_in[0];
  const int*   ei   = (const int*)d_in[1];
  const float* w0   = (const float*)d_in[2];
  const float* ats0 = (const float*)d_in[4];
  const float* atd0 = (const float*)d_in[5];
  const float* bn1w = (const float*)d_in[6];
  const float* bn1b = (const float*)d_in[7];
  const float* w2   = (const float*)d_in[8];
  const float* ats1 = (const float*)d_in[10];
  const float* atd1 = (const float*)d_in[11];
  const float* bn2w = (const float*)d_in[12];
  const float* bn2b = (const float*)d_in[13];
  const float* w4   = (const float*)d_in[14];
  const float* bn3w = (const float*)d_in[16];
  const float* bn3b = (const float*)d_in[17];
  const float* w6   = (const float*)d_in[18];
  const float* bn4w = (const float*)d_in[20];
  const float* bn4b = (const float*)d_in[21];
  const float* w8   = (const float*)d_in[22];
  const float* b8   = (const float*)d_in[23];

  // ---- explicit workspace layout (peak ~307.8 MB) ----
  const size_t REG = 153616384;  // EDGE_PAD*256*2
  char* ws = (char*)d_ws;
  bf16*  ef2b = (bf16*)ws;          // region0, live: build_ef2 .. ef3_inplace
  char*  R    = ws + REG;           // region1 (multi-use)
  float* hbuf  = (float*)(R);                 // node GEMM out / later PQ
  bf16*  xb    = (bf16*)(R + 61603840);
  bf16*  x1b   = (bf16*)(R + 65454080);
  bf16*  xrb   = (bf16*)(R + 73154560);       // NODE_PAD rows, zero-padded
  float* a_s   = (float*)(R + 80855040);
  float* a_d   = (float*)(R + 81335040);
  u32*   amaxU = (u32*)  (R + 81815040);
  float* denom = (float*)(R + 82295040);      // contiguous with amaxU
  float* alphaE= (float*)(R + 82775040);
  float* agg   = (float*)(R + 87575040);
  float* PQ    = hbuf;
  bf16*  y2b   = (bf16*)R;                    // GEMM2 out, overwrites node stuff
  char*  S     = ws + 2 * REG;
  bf16*  w0b   = (bf16*)(S);
  bf16*  w2b   = (bf16*)(S + 65536);
  bf16*  w45b  = (bf16*)(S + 196608);
  bf16*  w6b   = (bf16*)(S + 327680);
  bf16*  w8pb  = (bf16*)(S + 458752);
  float* stats1= (float*)(S + 524288);
  float* stats2= (float*)(S + 526336);
  const size_t needed = 2 * REG + 528384;
  if (ws_size < needed) {  // graceful, distinguishable failure (absmax ~3e38)
    fillpat<<<(out_size + 255) / 256, 256, 0, stream>>>((u32*)d_out, 0x7F7F7F7Fu, out_size);
    return;
  }

  // ---- convert inputs/weights to bf16 (padded) ----
  cvt_bf16_pad<<<(NODE_PAD * 64 + 255) / 256, 256, 0, stream>>>(x, xb, NNODES, NODE_PAD * 64, 64);
  cvt_bf16_pad<<<(512 * 64 + 255) / 256, 256, 0, stream>>>(w0, w0b, 512, 512 * 64, 64);
  cvt_bf16_pad<<<(512 * 128 + 255) / 256, 256, 0, stream>>>(w2, w2b, 512, 512 * 128, 128);
  cvt_w45<<<(512 * 128 + 255) / 256, 256, 0, stream>>>(w4, w45b);
  cvt_bf16_pad<<<(256 * 256 + 255) / 256, 256, 0, stream>>>(w6, w6b, 256, 256 * 256, 256);
  cvt_bf16_pad<<<(128 * 256 + 255) / 256, 256, 0, stream>>>(w8, w8pb, 86, 128 * 256, 256);

  const int etb = (NEDGES * 4 + 255) / 256;

  // ---- GAT layer 1 ----
  gemm_bt<false><<<dim3(NODE_PAD / 128, 4), 256, 0, stream>>>(xb, w0b, hbuf, 64, 512, NODE_PAD, 512, nullptr);
  att_reduce<<<NNODES, 256, 0, stream>>>(hbuf, ats0, atd0, a_s, a_d);
  zfill<<<(240000 + 255) / 256, 256, 0, stream>>>(amaxU, 240000);  // amaxU+denom
  zfill<<<(3840000 + 255) / 256, 256, 0, stream>>>((u32*)agg, 3840000);
  edge_alpha_max<<<etb, 256, 0, stream>>>(ei, a_s, a_d, alphaE, amaxU);
  edge_exp_sum<<<etb, 256, 0, stream>>>(ei, alphaE, amaxU, denom);
  edge_scatter<<<NEDGES / 2, 256, 0, stream>>>(ei, hbuf, alphaE, denom, agg);
  zfill<<<2, 256, 0, stream>>>((u32*)stats1, 512);
  col_stats<<<NODE_PAD / 128, 128, 0, stream>>>(agg, stats1, NNODES, 128, 128);
  bn_relu_node<<<NODE_PAD * 128 / 256, 256, 0, stream>>>(agg, stats1, bn1w, bn1b, x1b);

  // ---- GAT layer 2 ----
  gemm_bt<false><<<dim3(NODE_PAD / 128, 4), 256, 0, stream>>>(x1b, w2b, hbuf, 128, 512, NODE_PAD, 512, nullptr);
  att_reduce<<<NNODES, 256, 0, stream>>>(hbuf, ats1, atd1, a_s, a_d);
  zfill<<<(240000 + 255) / 256, 256, 0, stream>>>(amaxU, 240000);
  zfill<<<(3840000 + 255) / 256, 256, 0, stream>>>((u32*)agg, 3840000);
  edge_alpha_max<<<etb, 256, 0, stream>>>(ei, a_s, a_d, alphaE, amaxU);
  edge_exp_sum<<<etb, 256, 0, stream>>>(ei, alphaE, amaxU, denom);
  edge_scatter<<<NEDGES / 2, 256, 0, stream>>>(ei, hbuf, alphaE, denom, agg);
  zfill<<<2, 256, 0, stream>>>((u32*)stats1, 512);
  col_stats<<<NODE_PAD / 128, 128, 0, stream>>>(agg, stats1, NNODES, 128, 128);
  bn_res_relu_node<<<NODE_PAD * 128 / 256, 256, 0, stream>>>(agg, stats1, bn2w, bn2b, x1b, xrb);

  // ---- edge MLP ----
  // PQ[n, 0:256]=xr@w4L^T, PQ[n,256:512]=xr@w4R^T   (node-sized GEMM, K=128)
  gemm_bt<false><<<dim3(NODE_PAD / 128, 4), 256, 0, stream>>>(xrb, w45b, PQ, 128, 512, NODE_PAD, 512, nullptr);
  zfill<<<2, 256, 0, stream>>>((u32*)stats1, 512);
  e_stats<<<(NEDGES + 511) / 512, 256, 0, stream>>>(ei, PQ, stats1);
  build_ef2<<<EDGE_PAD, 256, 0, stream>>>(ei, PQ, xrb, stats1, bn3w, bn3b, ef2b);
  gemm_bt<true><<<dim3(EDGE_PAD / 128, 2), 256, 0, stream>>>(ef2b, w6b, y2b, 256, 256, EDGE_PAD, 256, nullptr);
  zfill<<<2, 256, 0, stream>>>((u32*)stats2, 512);
  col_stats_bf16<<<(NEDGES + 511) / 512, 256, 0, stream>>>(y2b, stats2, NEDGES, 256, 512);
  ef3_inplace<<<NEDGES / 8, 256, 0, stream>>>(y2b, ef2b, stats2, bn4w, bn4b);
  gemm_bt<false><<<dim3(EDGE_PAD / 128, 1), 256, 0, stream>>>(y2b, w8pb, (float*)d_out, 256, 86, NEDGES, 86, b8);
}

// Round 3
// 1292.336 us; speedup vs baseline: 1.1130x; 1.1130x over previous
//
#include <hip/hip_runtime.h>
#include <hip/hip_bf16.h>
#include <stdint.h>

typedef __hip_bfloat16 bf16;
typedef unsigned int u32;
typedef __attribute__((ext_vector_type(8))) short short8;
typedef __attribute__((ext_vector_type(4))) short short4v;
typedef __attribute__((ext_vector_type(4))) float f32x4;

#define NNODES 30000
#define NEDGES 300000
#define NODE_PAD 30080   // 235*128
#define EDGE_PAD 300032  // 2344*128
#define NEG_SLOPE 0.2f
#define BN_EPS 1e-5f

__device__ __forceinline__ float b2f(short s) {
  u32 u = ((u32)(unsigned short)s) << 16;
  return __uint_as_float(u);
}
__device__ __forceinline__ short f2b(float f) {
  bf16 h = __float2bfloat16(f);
  return *(short*)&h;
}

__device__ __forceinline__ void gload16(const void* g, void* l) {
  __builtin_amdgcn_global_load_lds(
      (__attribute__((address_space(1))) unsigned int*)(uintptr_t)g,
      (__attribute__((address_space(3))) unsigned int*)(uintptr_t)l, 16, 0, 0);
}

// ---------------- tiny utility kernels ----------------

__global__ void zfill(u32* __restrict__ p, int n) {
  int i = blockIdx.x * 256 + threadIdx.x;
  if (i < n) p[i] = 0u;
}

__global__ void fillpat(u32* __restrict__ p, u32 v, int n) {
  int i = blockIdx.x * 256 + threadIdx.x;
  if (i < n) p[i] = v;
}

__global__ void cvt_bf16_pad(const float* __restrict__ src, bf16* __restrict__ dst,
                             int rows_valid, int total, int cols) {
  int i = blockIdx.x * 256 + threadIdx.x;
  if (i >= total) return;
  int r = i / cols;
  float v = (r < rows_valid) ? src[i] : 0.f;
  dst[i] = __float2bfloat16(v);
}

// w45[n][k] = n<256 ? w4[n][k] : w4[n-256][128+k]
__global__ void cvt_w45(const float* __restrict__ w4, bf16* __restrict__ w45b) {
  int i = blockIdx.x * 256 + threadIdx.x;
  if (i >= 512 * 128) return;
  int n = i >> 7, k = i & 127;
  float v = (n < 256) ? w4[n * 256 + k] : w4[(n - 256) * 256 + 128 + k];
  w45b[i] = __float2bfloat16(v);
}

// ---------------- GEMM: C[M,N] = A[M,K] @ B[N,K]^T  (bf16 in) ----------------
// 128x128 tile, BK=64, 4 waves (2x2), wave = 4x4 frags of 16x16x32 MFMA.
// Optional fused column sum/sumsq (STATS) -> statsOut[col], statsOut[256+col].
template <bool BF16OUT, bool STATS>
__global__ __launch_bounds__(256) void gemm_bt(
    const bf16* __restrict__ A, const bf16* __restrict__ B, void* __restrict__ Cout,
    int K, int ldc, int Mvalid, int Nvalid, const float* __restrict__ bias,
    float* __restrict__ statsOut) {
  __shared__ __align__(16) short sm[2][128 * 64];
  const int tid = threadIdx.x;
  const int lane = tid & 63;
  const int wid = tid >> 6;
  const int wr = wid >> 1, wc = wid & 1;
  const size_t arow0 = (size_t)blockIdx.x * 128;
  const size_t brow0 = (size_t)blockIdx.y * 128;
  f32x4 acc[4][4] = {};
  const int nk = K >> 6;
  for (int kt = 0; kt < nk; ++kt) {
    const int kbase = kt * 64;
#pragma unroll
    for (int i = 0; i < 4; ++i) {
      int s = i * 256 + tid;
      int row = s >> 3;
      int c8l = (s & 7) ^ (row & 7);
      gload16(A + (arow0 + row) * K + kbase + c8l * 8, &sm[0][s * 8]);
      gload16(B + (brow0 + row) * K + kbase + c8l * 8, &sm[1][s * 8]);
    }
    __syncthreads();
#pragma unroll
    for (int ks = 0; ks < 2; ++ks) {
      short8 af[4], bfr[4];
      const int cg = ks * 4 + (lane >> 4);
#pragma unroll
      for (int m = 0; m < 4; ++m) {
        int row = wr * 64 + m * 16 + (lane & 15);
        af[m] = *(const short8*)&sm[0][row * 64 + ((cg ^ (row & 7)) << 3)];
      }
#pragma unroll
      for (int n = 0; n < 4; ++n) {
        int row = wc * 64 + n * 16 + (lane & 15);
        bfr[n] = *(const short8*)&sm[1][row * 64 + ((cg ^ (row & 7)) << 3)];
      }
#pragma unroll
      for (int m = 0; m < 4; ++m)
#pragma unroll
        for (int n = 0; n < 4; ++n)
          acc[m][n] = __builtin_amdgcn_mfma_f32_16x16x32_bf16(af[m], bfr[n], acc[m][n], 0, 0, 0);
    }
    __syncthreads();
  }
  if constexpr (STATS) {
    // per-column sum & sumsq over this block's 128 rows (pad rows are exact 0)
    float* smS = (float*)&sm[0][0];   // [2][128]
    float* smQ = smS + 256;           // [2][128]
#pragma unroll
    for (int n = 0; n < 4; ++n) {
      float s = 0.f, q = 0.f;
#pragma unroll
      for (int m = 0; m < 4; ++m)
#pragma unroll
        for (int r = 0; r < 4; ++r) {
          float v = acc[m][n][r];
          s += v;
          q += v * v;
        }
      s += __shfl_xor(s, 16); s += __shfl_xor(s, 32);
      q += __shfl_xor(q, 16); q += __shfl_xor(q, 32);
      if (lane < 16) {
        int col = wc * 64 + n * 16 + lane;
        smS[wr * 128 + col] = s;
        smQ[wr * 128 + col] = q;
      }
    }
    __syncthreads();
    if (tid < 128) {
      atomicAdd(&statsOut[brow0 + tid], smS[tid] + smS[128 + tid]);
      atomicAdd(&statsOut[256 + brow0 + tid], smQ[tid] + smQ[128 + tid]);
    }
  }
  const int rbase = (int)arow0 + wr * 64 + (lane >> 4) * 4;
  const int cbase = (int)brow0 + wc * 64 + (lane & 15);
#pragma unroll
  for (int m = 0; m < 4; ++m) {
#pragma unroll
    for (int n = 0; n < 4; ++n) {
      int col = cbase + n * 16;
      if (col >= Nvalid) continue;
      float badd = bias ? bias[col] : 0.f;
#pragma unroll
      for (int r = 0; r < 4; ++r) {
        int row = rbase + m * 16 + r;
        if (row < Mvalid) {
          if constexpr (BF16OUT)
            ((bf16*)Cout)[(size_t)row * ldc + col] = __float2bfloat16(acc[m][n][r] + badd);
          else
            ((float*)Cout)[(size_t)row * ldc + col] = acc[m][n][r] + badd;
        }
      }
    }
  }
}

// ---------------- GAT pieces ----------------

__global__ __launch_bounds__(256) void att_reduce(
    const float* __restrict__ h, const float* __restrict__ ats, const float* __restrict__ atd,
    float* __restrict__ a_s, float* __restrict__ a_d) {
  int n = blockIdx.x;
  int lane = threadIdx.x & 63;
  int hd = threadIdx.x >> 6;
  const float* hp = h + (size_t)n * 512 + hd * 128;
  const float* sw = ats + hd * 128;
  const float* dw = atd + hd * 128;
  float h1 = hp[lane], h2 = hp[lane + 64];
  float s = h1 * sw[lane] + h2 * sw[lane + 64];
  float d = h1 * dw[lane] + h2 * dw[lane + 64];
#pragma unroll
  for (int off = 32; off > 0; off >>= 1) {
    s += __shfl_down(s, off);
    d += __shfl_down(d, off);
  }
  if (lane == 0) {
    a_s[n * 4 + hd] = s;
    a_d[n * 4 + hd] = d;
  }
}

__global__ void edge_alpha_max(const int* __restrict__ ei, const float* __restrict__ a_s,
                               const float* __restrict__ a_d, float* __restrict__ alphaE,
                               u32* __restrict__ amaxU) {
  int t = blockIdx.x * 256 + threadIdx.x;
  if (t >= NEDGES * 4) return;
  int e = t >> 2, h = t & 3;
  int s = ei[e], d = ei[NEDGES + e];
  float a = a_s[s * 4 + h] + a_d[d * 4 + h];
  a = (a > 0.f) ? a : NEG_SLOPE * a;
  alphaE[t] = a;
  u32 bits = __float_as_uint(a);
  u32 key = bits ^ (((int)bits < 0) ? 0xFFFFFFFFu : 0x80000000u);
  atomicMax(&amaxU[d * 4 + h], key);
}

__global__ void edge_exp_sum(const int* __restrict__ ei, float* __restrict__ alphaE,
                             const u32* __restrict__ amaxU, float* __restrict__ denom) {
  int t = blockIdx.x * 256 + threadIdx.x;
  if (t >= NEDGES * 4) return;
  int e = t >> 2, h = t & 3;
  int d = ei[NEDGES + e];
  u32 k = amaxU[d * 4 + h];
  u32 bits = (k & 0x80000000u) ? (k ^ 0x80000000u) : ~k;
  float am = __uint_as_float(bits);
  float ev = __expf(alphaE[t] - am);
  alphaE[t] = ev;
  atomicAdd(&denom[d * 4 + h], ev);
}

__global__ void edge_scatter(const int* __restrict__ ei, const float* __restrict__ hbuf,
                             const float* __restrict__ evals, const float* __restrict__ denom,
                             float* __restrict__ agg) {
  int e = blockIdx.x * 2 + (threadIdx.x >> 7);
  int d = threadIdx.x & 127;
  int s = ei[e], dd = ei[NEDGES + e];
  float sum = 0.f;
#pragma unroll
  for (int h = 0; h < 4; ++h) {
    float coef = evals[e * 4 + h] / denom[dd * 4 + h];
    sum += hbuf[(size_t)s * 512 + h * 128 + d] * coef;
  }
  atomicAdd(&agg[dd * 128 + d], sum * 0.25f);
}

// ---------------- BatchNorm pieces ----------------

// column stats for [rows][128] fp32; 64 rows/block, float4 per thread, LDS reduce
__global__ __launch_bounds__(256) void col_stats128(const float* __restrict__ X,
                                                    float* __restrict__ stats, int rows) {
  __shared__ float smS[8][128], smQ[8][128];
  int t = threadIdx.x;
  int sub = t >> 5;
  int c4 = (t & 31) * 4;
  int rend = blockIdx.x * 64 + 64;
  if (rend > rows) rend = rows;
  f32x4 s = {}, q = {};
  for (int r = blockIdx.x * 64 + sub; r < rend; r += 8) {
    f32x4 v = *(const f32x4*)&X[(size_t)r * 128 + c4];
    s += v;
    q += v * v;
  }
  *(f32x4*)&smS[sub][c4] = s;
  *(f32x4*)&smQ[sub][c4] = q;
  __syncthreads();
  if (t < 128) {
    float ts = 0.f, tq = 0.f;
#pragma unroll
    for (int g = 0; g < 8; ++g) { ts += smS[g][t]; tq += smQ[g][t]; }
    atomicAdd(&stats[t], ts);
    atomicAdd(&stats[128 + t], tq);
  }
}

__global__ void bn_relu_node(const float* __restrict__ agg, const float* __restrict__ stats,
                             const float* __restrict__ w, const float* __restrict__ b,
                             bf16* __restrict__ xout) {
  int i = blockIdx.x * 256 + threadIdx.x;
  if (i >= NODE_PAD * 128) return;
  int r = i >> 7, c = i & 127;
  float v = 0.f;
  if (r < NNODES) {
    float m = stats[c] * (1.f / NNODES);
    float var = stats[128 + c] * (1.f / NNODES) - m * m;
    float rstd = rsqrtf(var + BN_EPS);
    v = fmaxf((agg[i] - m) * rstd * w[c] + b[c], 0.f);
  }
  xout[i] = __float2bfloat16(v);
}

__global__ void bn_res_relu_node(const float* __restrict__ agg, const float* __restrict__ stats,
                                 const float* __restrict__ w, const float* __restrict__ b,
                                 const bf16* __restrict__ x1b, bf16* __restrict__ xrb) {
  int i = blockIdx.x * 256 + threadIdx.x;
  if (i >= NODE_PAD * 128) return;
  int r = i >> 7, c = i & 127;
  float v = 0.f;
  if (r < NNODES) {
    float m = stats[c] * (1.f / NNODES);
    float var = stats[128 + c] * (1.f / NNODES) - m * m;
    float rstd = rsqrtf(var + BN_EPS);
    v = fmaxf((agg[i] - m) * rstd * w[c] + b[c] + __bfloat162float(x1b[i]), 0.f);
  }
  xrb[i] = __float2bfloat16(v);
}

// ---------------- edge-MLP pieces (y1 = P[src] + Q[dst], never materialized) --

// stats of y1 over edges; 128 edges/block, 4 in flight, float4 cols, LDS reduce
__global__ __launch_bounds__(256) void e_stats(const int* __restrict__ ei,
                                               const float* __restrict__ PQ,
                                               float* __restrict__ stats) {
  __shared__ f32x4 smS[256], smQ[256];
  int t = threadIdx.x;
  int sub = t >> 6;
  int c4 = (t & 63) * 4;
  int e0 = blockIdx.x * 128;
  int eend = e0 + 128;
  if (eend > NEDGES) eend = NEDGES;
  f32x4 s = {}, q = {};
  for (int e = e0 + sub; e < eend; e += 4) {
    int sn = ei[e], dn = ei[NEDGES + e];
    f32x4 p = *(const f32x4*)&PQ[(size_t)sn * 512 + c4];
    f32x4 qq = *(const f32x4*)&PQ[(size_t)dn * 512 + 256 + c4];
    f32x4 v = p + qq;
    s += v;
    q += v * v;
  }
  smS[t] = s;
  smQ[t] = q;
  __syncthreads();
  if (t < 64) {
    f32x4 ts = smS[t] + smS[t + 64] + smS[t + 128] + smS[t + 192];
    f32x4 tq = smQ[t] + smQ[t + 64] + smQ[t + 128] + smQ[t + 192];
#pragma unroll
    for (int j = 0; j < 4; ++j) {
      atomicAdd(&stats[t * 4 + j], ts[j]);
      atomicAdd(&stats[256 + t * 4 + j], tq[j]);
    }
  }
}

// ef2[e,c] = relu(bn3(P[src]+Q[dst]) + ef1[e,c]); 4 edges per block, float4 cols
__global__ __launch_bounds__(256) void build_ef2(const int* __restrict__ ei,
                                                 const float* __restrict__ PQ,
                                                 const bf16* __restrict__ xrb,
                                                 const float* __restrict__ stats,
                                                 const float* __restrict__ w,
                                                 const float* __restrict__ b,
                                                 bf16* __restrict__ ef2) {
  int t = threadIdx.x;
  int e = blockIdx.x * 4 + (t >> 6);
  int c4 = (t & 63) * 4;
  short4v out = {};
  if (e < NEDGES) {
    int sn = ei[e], dn = ei[NEDGES + e];
    f32x4 p = *(const f32x4*)&PQ[(size_t)sn * 512 + c4];
    f32x4 qq = *(const f32x4*)&PQ[(size_t)dn * 512 + 256 + c4];
    int node = (c4 < 128) ? sn : dn;
    short4v res = *(const short4v*)&xrb[(size_t)node * 128 + (c4 & 127)];
#pragma unroll
    for (int j = 0; j < 4; ++j) {
      int c = c4 + j;
      float m = stats[c] * (1.f / NEDGES);
      float var = stats[256 + c] * (1.f / NEDGES) - m * m;
      float rstd = rsqrtf(var + BN_EPS);
      float v = (p[j] + qq[j] - m) * rstd * w[c] + b[c] + b2f(res[j]);
      out[j] = f2b(fmaxf(v, 0.f));
    }
  }
  *(short4v*)&ef2[(size_t)e * 256 + c4] = out;
}

// y2 <- relu(bn4(y2) + ef2), in place, 8 elems/thread
__global__ void ef3_inplace(bf16* __restrict__ y2, const bf16* __restrict__ ef2,
                            const float* __restrict__ stats, const float* __restrict__ w,
                            const float* __restrict__ b) {
  int t = blockIdx.x * 256 + threadIdx.x;
  size_t base = (size_t)t * 8;
  int c0 = (int)(base & 255);
  short8 yv = *(const short8*)(y2 + base);
  short8 ev = *(const short8*)(ef2 + base);
  short8 out;
#pragma unroll
  for (int j = 0; j < 8; ++j) {
    int c = c0 + j;
    float m = stats[c] * (1.f / NEDGES);
    float var = stats[256 + c] * (1.f / NEDGES) - m * m;
    float rstd = rsqrtf(var + BN_EPS);
    float v = fmaxf((b2f(yv[j]) - m) * rstd * w[c] + b[c] + b2f(ev[j]), 0.f);
    out[j] = f2b(v);
  }
  *(short8*)(y2 + base) = out;
}

// ---------------- launch ----------------

extern "C" void kernel_launch(void* const* d_in, const int* in_sizes, int n_in,
                              void* d_out, int out_size, void* d_ws, size_t ws_size,
                              hipStream_t stream) {
  const float* x    = (const float*)d_in[0];
  const int*   ei   = (const int*)d_in[1];
  const float* w0   = (const float*)d_in[2];
  const float* ats0 = (const float*)d_in[4];
  const float* atd0 = (const float*)d_in[5];
  const float* bn1w = (const float*)d_in[6];
  const float* bn1b = (const float*)d_in[7];
  const float* w2   = (const float*)d_in[8];
  const float* ats1 = (const float*)d_in[10];
  const float* atd1 = (const float*)d_in[11];
  const float* bn2w = (const float*)d_in[12];
  const float* bn2b = (const float*)d_in[13];
  const float* w4   = (const float*)d_in[14];
  const float* bn3w = (const float*)d_in[16];
  const float* bn3b = (const float*)d_in[17];
  const float* w6   = (const float*)d_in[18];
  const float* bn4w = (const float*)d_in[20];
  const float* bn4b = (const float*)d_in[21];
  const float* w8   = (const float*)d_in[22];
  const float* b8   = (const float*)d_in[23];

  // ---- explicit workspace layout (peak ~307.8 MB) ----
  const size_t REG = 153616384;  // EDGE_PAD*256*2
  char* ws = (char*)d_ws;
  bf16*  ef2b = (bf16*)ws;
  char*  R    = ws + REG;
  float* hbuf  = (float*)(R);
  bf16*  xb    = (bf16*)(R + 61603840);
  bf16*  x1b   = (bf16*)(R + 65454080);
  bf16*  xrb   = (bf16*)(R + 73154560);
  float* a_s   = (float*)(R + 80855040);
  float* a_d   = (float*)(R + 81335040);
  u32*   amaxU = (u32*)  (R + 81815040);
  float* denom = (float*)(R + 82295040);
  float* alphaE= (float*)(R + 82775040);
  float* agg   = (float*)(R + 87575040);
  float* PQ    = hbuf;
  bf16*  y2b   = (bf16*)R;
  char*  S     = ws + 2 * REG;
  bf16*  w0b   = (bf16*)(S);
  bf16*  w2b   = (bf16*)(S + 65536);
  bf16*  w45b  = (bf16*)(S + 196608);
  bf16*  w6b   = (bf16*)(S + 327680);
  bf16*  w8pb  = (bf16*)(S + 458752);
  float* stats1= (float*)(S + 524288);
  float* stats2= (float*)(S + 526336);
  const size_t needed = 2 * REG + 528384;
  if (ws_size < needed) {
    fillpat<<<(out_size + 255) / 256, 256, 0, stream>>>((u32*)d_out, 0x7F7F7F7Fu, out_size);
    return;
  }

  // ---- convert inputs/weights to bf16 (padded) ----
  cvt_bf16_pad<<<(NODE_PAD * 64 + 255) / 256, 256, 0, stream>>>(x, xb, NNODES, NODE_PAD * 64, 64);
  cvt_bf16_pad<<<(512 * 64 + 255) / 256, 256, 0, stream>>>(w0, w0b, 512, 512 * 64, 64);
  cvt_bf16_pad<<<(512 * 128 + 255) / 256, 256, 0, stream>>>(w2, w2b, 512, 512 * 128, 128);
  cvt_w45<<<(512 * 128 + 255) / 256, 256, 0, stream>>>(w4, w45b);
  cvt_bf16_pad<<<(256 * 256 + 255) / 256, 256, 0, stream>>>(w6, w6b, 256, 256 * 256, 256);
  cvt_bf16_pad<<<(128 * 256 + 255) / 256, 256, 0, stream>>>(w8, w8pb, 86, 128 * 256, 256);

  const int etb = (NEDGES * 4 + 255) / 256;

  // ---- GAT layer 1 ----
  gemm_bt<false, false><<<dim3(NODE_PAD / 128, 4), 256, 0, stream>>>(xb, w0b, hbuf, 64, 512, NODE_PAD, 512, nullptr, nullptr);
  att_reduce<<<NNODES, 256, 0, stream>>>(hbuf, ats0, atd0, a_s, a_d);
  zfill<<<(240000 + 255) / 256, 256, 0, stream>>>(amaxU, 240000);
  zfill<<<(3840000 + 255) / 256, 256, 0, stream>>>((u32*)agg, 3840000);
  edge_alpha_max<<<etb, 256, 0, stream>>>(ei, a_s, a_d, alphaE, amaxU);
  edge_exp_sum<<<etb, 256, 0, stream>>>(ei, alphaE, amaxU, denom);
  edge_scatter<<<NEDGES / 2, 256, 0, stream>>>(ei, hbuf, alphaE, denom, agg);
  zfill<<<1, 256, 0, stream>>>((u32*)stats1, 256);
  col_stats128<<<(NNODES + 63) / 64, 256, 0, stream>>>(agg, stats1, NNODES);
  bn_relu_node<<<NODE_PAD * 128 / 256, 256, 0, stream>>>(agg, stats1, bn1w, bn1b, x1b);

  // ---- GAT layer 2 ----
  gemm_bt<false, false><<<dim3(NODE_PAD / 128, 4), 256, 0, stream>>>(x1b, w2b, hbuf, 128, 512, NODE_PAD, 512, nullptr, nullptr);
  att_reduce<<<NNODES, 256, 0, stream>>>(hbuf, ats1, atd1, a_s, a_d);
  zfill<<<(240000 + 255) / 256, 256, 0, stream>>>(amaxU, 240000);
  zfill<<<(3840000 + 255) / 256, 256, 0, stream>>>((u32*)agg, 3840000);
  edge_alpha_max<<<etb, 256, 0, stream>>>(ei, a_s, a_d, alphaE, amaxU);
  edge_exp_sum<<<etb, 256, 0, stream>>>(ei, alphaE, amaxU, denom);
  edge_scatter<<<NEDGES / 2, 256, 0, stream>>>(ei, hbuf, alphaE, denom, agg);
  zfill<<<1, 256, 0, stream>>>((u32*)stats1, 256);
  col_stats128<<<(NNODES + 63) / 64, 256, 0, stream>>>(agg, stats1, NNODES);
  bn_res_relu_node<<<NODE_PAD * 128 / 256, 256, 0, stream>>>(agg, stats1, bn2w, bn2b, x1b, xrb);

  // ---- edge MLP ----
  gemm_bt<false, false><<<dim3(NODE_PAD / 128, 4), 256, 0, stream>>>(xrb, w45b, PQ, 128, 512, NODE_PAD, 512, nullptr, nullptr);
  zfill<<<2, 256, 0, stream>>>((u32*)stats1, 512);
  e_stats<<<(NEDGES + 127) / 128, 256, 0, stream>>>(ei, PQ, stats1);
  build_ef2<<<EDGE_PAD / 4, 256, 0, stream>>>(ei, PQ, xrb, stats1, bn3w, bn3b, ef2b);
  zfill<<<2, 256, 0, stream>>>((u32*)stats2, 512);
  gemm_bt<true, true><<<dim3(EDGE_PAD / 128, 2), 256, 0, stream>>>(ef2b, w6b, y2b, 256, 256, EDGE_PAD, 256, nullptr, stats2);
  ef3_inplace<<<NEDGES / 8, 256, 0, stream>>>(y2b, ef2b, stats2, bn4w, bn4b);
  gemm_bt<false, false><<<dim3(EDGE_PAD / 128, 1), 256, 0, stream>>>(y2b, w8pb, (float*)d_out, 256, 86, NEDGES, 86, b8, nullptr);
}

// Round 4
// 1210.527 us; speedup vs baseline: 1.1883x; 1.0676x over previous
//
#include <hip/hip_runtime.h>
#include <hip/hip_bf16.h>
#include <stdint.h>

typedef __hip_bfloat16 bf16;
typedef unsigned int u32;
typedef __attribute__((ext_vector_type(8))) short short8;
typedef __attribute__((ext_vector_type(4))) short short4v;
typedef __attribute__((ext_vector_type(4))) float f32x4;

#define NNODES 30000
#define NEDGES 300000
#define NODE_PAD 30080   // 235*128
#define EDGE_PAD 300032  // 2344*128
#define NEG_SLOPE 0.2f
#define BN_EPS 1e-5f

__device__ __forceinline__ float b2f(short s) {
  u32 u = ((u32)(unsigned short)s) << 16;
  return __uint_as_float(u);
}
__device__ __forceinline__ short f2b(float f) {
  bf16 h = __float2bfloat16(f);
  return *(short*)&h;
}

__device__ __forceinline__ void gload16(const void* g, void* l) {
  __builtin_amdgcn_global_load_lds(
      (__attribute__((address_space(1))) unsigned int*)(uintptr_t)g,
      (__attribute__((address_space(3))) unsigned int*)(uintptr_t)l, 16, 0, 0);
}

// ---------------- tiny utility kernels ----------------

__global__ void zfill(u32* __restrict__ p, int n) {
  int i = blockIdx.x * 256 + threadIdx.x;
  if (i < n) p[i] = 0u;
}

__global__ void fillpat(u32* __restrict__ p, u32 v, int n) {
  int i = blockIdx.x * 256 + threadIdx.x;
  if (i < n) p[i] = v;
}

__global__ void cvt_bf16_pad(const float* __restrict__ src, bf16* __restrict__ dst,
                             int rows_valid, int total, int cols) {
  int i = blockIdx.x * 256 + threadIdx.x;
  if (i >= total) return;
  int r = i / cols;
  float v = (r < rows_valid) ? src[i] : 0.f;
  dst[i] = __float2bfloat16(v);
}

// w45[n][k] = n<256 ? w4[n][k] : w4[n-256][128+k]
__global__ void cvt_w45(const float* __restrict__ w4, bf16* __restrict__ w45b) {
  int i = blockIdx.x * 256 + threadIdx.x;
  if (i >= 512 * 128) return;
  int n = i >> 7, k = i & 127;
  float v = (n < 256) ? w4[n * 256 + k] : w4[(n - 256) * 256 + 128 + k];
  w45b[i] = __float2bfloat16(v);
}

// ---------------- GEMM: C[M,N] = A[M,K] @ B[N,K]^T  (bf16 in) ----------------
template <bool BF16OUT, bool STATS>
__global__ __launch_bounds__(256) void gemm_bt(
    const bf16* __restrict__ A, const bf16* __restrict__ B, void* __restrict__ Cout,
    int K, int ldc, int Mvalid, int Nvalid, const float* __restrict__ bias,
    float* __restrict__ statsOut) {
  __shared__ __align__(16) short sm[2][128 * 64];
  const int tid = threadIdx.x;
  const int lane = tid & 63;
  const int wid = tid >> 6;
  const int wr = wid >> 1, wc = wid & 1;
  const size_t arow0 = (size_t)blockIdx.x * 128;
  const size_t brow0 = (size_t)blockIdx.y * 128;
  f32x4 acc[4][4] = {};
  const int nk = K >> 6;
  for (int kt = 0; kt < nk; ++kt) {
    const int kbase = kt * 64;
#pragma unroll
    for (int i = 0; i < 4; ++i) {
      int s = i * 256 + tid;
      int row = s >> 3;
      int c8l = (s & 7) ^ (row & 7);
      gload16(A + (arow0 + row) * K + kbase + c8l * 8, &sm[0][s * 8]);
      gload16(B + (brow0 + row) * K + kbase + c8l * 8, &sm[1][s * 8]);
    }
    __syncthreads();
#pragma unroll
    for (int ks = 0; ks < 2; ++ks) {
      short8 af[4], bfr[4];
      const int cg = ks * 4 + (lane >> 4);
#pragma unroll
      for (int m = 0; m < 4; ++m) {
        int row = wr * 64 + m * 16 + (lane & 15);
        af[m] = *(const short8*)&sm[0][row * 64 + ((cg ^ (row & 7)) << 3)];
      }
#pragma unroll
      for (int n = 0; n < 4; ++n) {
        int row = wc * 64 + n * 16 + (lane & 15);
        bfr[n] = *(const short8*)&sm[1][row * 64 + ((cg ^ (row & 7)) << 3)];
      }
#pragma unroll
      for (int m = 0; m < 4; ++m)
#pragma unroll
        for (int n = 0; n < 4; ++n)
          acc[m][n] = __builtin_amdgcn_mfma_f32_16x16x32_bf16(af[m], bfr[n], acc[m][n], 0, 0, 0);
    }
    __syncthreads();
  }
  if constexpr (STATS) {
    float* smS = (float*)&sm[0][0];
    float* smQ = smS + 256;
#pragma unroll
    for (int n = 0; n < 4; ++n) {
      float s = 0.f, q = 0.f;
#pragma unroll
      for (int m = 0; m < 4; ++m)
#pragma unroll
        for (int r = 0; r < 4; ++r) {
          float v = acc[m][n][r];
          s += v;
          q += v * v;
        }
      s += __shfl_xor(s, 16); s += __shfl_xor(s, 32);
      q += __shfl_xor(q, 16); q += __shfl_xor(q, 32);
      if (lane < 16) {
        int col = wc * 64 + n * 16 + lane;
        smS[wr * 128 + col] = s;
        smQ[wr * 128 + col] = q;
      }
    }
    __syncthreads();
    if (tid < 128) {
      atomicAdd(&statsOut[brow0 + tid], smS[tid] + smS[128 + tid]);
      atomicAdd(&statsOut[256 + brow0 + tid], smQ[tid] + smQ[128 + tid]);
    }
  }
  const int rbase = (int)arow0 + wr * 64 + (lane >> 4) * 4;
  const int cbase = (int)brow0 + wc * 64 + (lane & 15);
#pragma unroll
  for (int m = 0; m < 4; ++m) {
#pragma unroll
    for (int n = 0; n < 4; ++n) {
      int col = cbase + n * 16;
      if (col >= Nvalid) continue;
      float badd = bias ? bias[col] : 0.f;
#pragma unroll
      for (int r = 0; r < 4; ++r) {
        int row = rbase + m * 16 + r;
        if (row < Mvalid) {
          if constexpr (BF16OUT)
            ((bf16*)Cout)[(size_t)row * ldc + col] = __float2bfloat16(acc[m][n][r] + badd);
          else
            ((float*)Cout)[(size_t)row * ldc + col] = acc[m][n][r] + badd;
        }
      }
    }
  }
}

// ---------------- GAT pieces ----------------

__global__ __launch_bounds__(256) void att_reduce(
    const float* __restrict__ h, const float* __restrict__ ats, const float* __restrict__ atd,
    float* __restrict__ a_s, float* __restrict__ a_d) {
  int n = blockIdx.x;
  int lane = threadIdx.x & 63;
  int hd = threadIdx.x >> 6;
  const float* hp = h + (size_t)n * 512 + hd * 128;
  const float* sw = ats + hd * 128;
  const float* dw = atd + hd * 128;
  float h1 = hp[lane], h2 = hp[lane + 64];
  float s = h1 * sw[lane] + h2 * sw[lane + 64];
  float d = h1 * dw[lane] + h2 * dw[lane + 64];
#pragma unroll
  for (int off = 32; off > 0; off >>= 1) {
    s += __shfl_down(s, off);
    d += __shfl_down(d, off);
  }
  if (lane == 0) {
    a_s[n * 4 + hd] = s;
    a_d[n * 4 + hd] = d;
  }
}

__global__ void edge_alpha_max(const int* __restrict__ ei, const float* __restrict__ a_s,
                               const float* __restrict__ a_d, float* __restrict__ alphaE,
                               u32* __restrict__ amaxU) {
  int t = blockIdx.x * 256 + threadIdx.x;
  if (t >= NEDGES * 4) return;
  int e = t >> 2, h = t & 3;
  int s = ei[e], d = ei[NEDGES + e];
  float a = a_s[s * 4 + h] + a_d[d * 4 + h];
  a = (a > 0.f) ? a : NEG_SLOPE * a;
  alphaE[t] = a;
  u32 bits = __float_as_uint(a);
  u32 key = bits ^ (((int)bits < 0) ? 0xFFFFFFFFu : 0x80000000u);
  atomicMax(&amaxU[d * 4 + h], key);
}

__global__ void edge_exp_sum(const int* __restrict__ ei, float* __restrict__ alphaE,
                             const u32* __restrict__ amaxU, float* __restrict__ denom) {
  int t = blockIdx.x * 256 + threadIdx.x;
  if (t >= NEDGES * 4) return;
  int e = t >> 2, h = t & 3;
  int d = ei[NEDGES + e];
  u32 k = amaxU[d * 4 + h];
  u32 bits = (k & 0x80000000u) ? (k ^ 0x80000000u) : ~k;
  float am = __uint_as_float(bits);
  float ev = __expf(alphaE[t] - am);
  alphaE[t] = ev;
  atomicAdd(&denom[d * 4 + h], ev);
}

__global__ void edge_scatter(const int* __restrict__ ei, const float* __restrict__ hbuf,
                             const float* __restrict__ evals, const float* __restrict__ denom,
                             float* __restrict__ agg) {
  int e = blockIdx.x * 2 + (threadIdx.x >> 7);
  int d = threadIdx.x & 127;
  int s = ei[e], dd = ei[NEDGES + e];
  float sum = 0.f;
#pragma unroll
  for (int h = 0; h < 4; ++h) {
    float coef = evals[e * 4 + h] / denom[dd * 4 + h];
    sum += hbuf[(size_t)s * 512 + h * 128 + d] * coef;
  }
  atomicAdd(&agg[dd * 128 + d], sum * 0.25f);
}

// ---------------- BatchNorm pieces ----------------

__global__ __launch_bounds__(256) void col_stats128(const float* __restrict__ X,
                                                    float* __restrict__ stats, int rows) {
  __shared__ float smS[8][128], smQ[8][128];
  int t = threadIdx.x;
  int sub = t >> 5;
  int c4 = (t & 31) * 4;
  int rend = blockIdx.x * 64 + 64;
  if (rend > rows) rend = rows;
  f32x4 s = {}, q = {};
  for (int r = blockIdx.x * 64 + sub; r < rend; r += 8) {
    f32x4 v = *(const f32x4*)&X[(size_t)r * 128 + c4];
    s += v;
    q += v * v;
  }
  *(f32x4*)&smS[sub][c4] = s;
  *(f32x4*)&smQ[sub][c4] = q;
  __syncthreads();
  if (t < 128) {
    float ts = 0.f, tq = 0.f;
#pragma unroll
    for (int g = 0; g < 8; ++g) { ts += smS[g][t]; tq += smQ[g][t]; }
    atomicAdd(&stats[t], ts);
    atomicAdd(&stats[128 + t], tq);
  }
}

__global__ void bn_relu_node(const float* __restrict__ agg, const float* __restrict__ stats,
                             const float* __restrict__ w, const float* __restrict__ b,
                             bf16* __restrict__ xout) {
  int i = blockIdx.x * 256 + threadIdx.x;
  if (i >= NODE_PAD * 128) return;
  int r = i >> 7, c = i & 127;
  float v = 0.f;
  if (r < NNODES) {
    float m = stats[c] * (1.f / NNODES);
    float var = stats[128 + c] * (1.f / NNODES) - m * m;
    float rstd = rsqrtf(var + BN_EPS);
    v = fmaxf((agg[i] - m) * rstd * w[c] + b[c], 0.f);
  }
  xout[i] = __float2bfloat16(v);
}

__global__ void bn_res_relu_node(const float* __restrict__ agg, const float* __restrict__ stats,
                                 const float* __restrict__ w, const float* __restrict__ b,
                                 const bf16* __restrict__ x1b, bf16* __restrict__ xrb) {
  int i = blockIdx.x * 256 + threadIdx.x;
  if (i >= NODE_PAD * 128) return;
  int r = i >> 7, c = i & 127;
  float v = 0.f;
  if (r < NNODES) {
    float m = stats[c] * (1.f / NNODES);
    float var = stats[128 + c] * (1.f / NNODES) - m * m;
    float rstd = rsqrtf(var + BN_EPS);
    v = fmaxf((agg[i] - m) * rstd * w[c] + b[c] + __bfloat162float(x1b[i]), 0.f);
  }
  xrb[i] = __float2bfloat16(v);
}

// ---------------- edge-MLP head ----------------
// Pass 1: gather y1 = P[src]+Q[dst] ONCE; write y1 (bf16) + column stats.
// 128 edges/block, 4 subgroups x (32 edges, unrolled by 4) -> 8 gathers in flight.
__global__ __launch_bounds__(256) void e_stats_mat(const int* __restrict__ ei,
                                                   const float* __restrict__ PQ,
                                                   bf16* __restrict__ y1out,
                                                   float* __restrict__ stats) {
  __shared__ f32x4 smS[256], smQ[256];
  int t = threadIdx.x;
  int sub = t >> 6;
  int c4 = (t & 63) * 4;
  int ebase = blockIdx.x * 128 + sub * 32;
  const float* Qp = PQ + 256;
  f32x4 s = {}, q = {};
#pragma unroll 1
  for (int i = 0; i < 32; i += 4) {
    int e = ebase + i;
    if (e + 3 < NEDGES) {
      int sn0 = ei[e], sn1 = ei[e + 1], sn2 = ei[e + 2], sn3 = ei[e + 3];
      int dn0 = ei[NEDGES + e], dn1 = ei[NEDGES + e + 1],
          dn2 = ei[NEDGES + e + 2], dn3 = ei[NEDGES + e + 3];
      f32x4 p0 = *(const f32x4*)&PQ[(size_t)sn0 * 512 + c4];
      f32x4 p1 = *(const f32x4*)&PQ[(size_t)sn1 * 512 + c4];
      f32x4 p2 = *(const f32x4*)&PQ[(size_t)sn2 * 512 + c4];
      f32x4 p3 = *(const f32x4*)&PQ[(size_t)sn3 * 512 + c4];
      f32x4 r0 = *(const f32x4*)&Qp[(size_t)dn0 * 512 + c4];
      f32x4 r1 = *(const f32x4*)&Qp[(size_t)dn1 * 512 + c4];
      f32x4 r2 = *(const f32x4*)&Qp[(size_t)dn2 * 512 + c4];
      f32x4 r3 = *(const f32x4*)&Qp[(size_t)dn3 * 512 + c4];
      f32x4 v0 = p0 + r0, v1 = p1 + r1, v2 = p2 + r2, v3 = p3 + r3;
      s += v0 + v1 + v2 + v3;
      q += v0 * v0 + v1 * v1 + v2 * v2 + v3 * v3;
      short4v o0, o1, o2, o3;
#pragma unroll
      for (int j = 0; j < 4; ++j) {
        o0[j] = f2b(v0[j]); o1[j] = f2b(v1[j]); o2[j] = f2b(v2[j]); o3[j] = f2b(v3[j]);
      }
      *(short4v*)&y1out[(size_t)e * 256 + c4] = o0;
      *(short4v*)&y1out[(size_t)(e + 1) * 256 + c4] = o1;
      *(short4v*)&y1out[(size_t)(e + 2) * 256 + c4] = o2;
      *(short4v*)&y1out[(size_t)(e + 3) * 256 + c4] = o3;
    } else {
      for (int j = 0; j < 4; ++j) {
        int ej = e + j;
        if (ej >= NEDGES) break;
        int sn = ei[ej], dn = ei[NEDGES + ej];
        f32x4 p = *(const f32x4*)&PQ[(size_t)sn * 512 + c4];
        f32x4 r = *(const f32x4*)&Qp[(size_t)dn * 512 + c4];
        f32x4 v = p + r;
        s += v;
        q += v * v;
        short4v o;
#pragma unroll
        for (int k = 0; k < 4; ++k) o[k] = f2b(v[k]);
        *(short4v*)&y1out[(size_t)ej * 256 + c4] = o;
      }
    }
  }
  smS[t] = s;
  smQ[t] = q;
  __syncthreads();
  if (t < 64) {
    f32x4 ts = smS[t] + smS[t + 64] + smS[t + 128] + smS[t + 192];
    f32x4 tq = smQ[t] + smQ[t + 64] + smQ[t + 128] + smQ[t + 192];
#pragma unroll
    for (int j = 0; j < 4; ++j) {
      atomicAdd(&stats[t * 4 + j], ts[j]);
      atomicAdd(&stats[256 + t * 4 + j], tq[j]);
    }
  }
}

// Pass 2: ef2 = relu(bn3(y1) + xr[src|dst]) IN PLACE on the y1 buffer.
// 8 edges/block, 32 threads/edge, short8 per thread; pad rows -> 0.
__global__ __launch_bounds__(256) void ef2_norm(const int* __restrict__ ei,
                                                const bf16* __restrict__ xrb,
                                                const float* __restrict__ stats,
                                                const float* __restrict__ w,
                                                const float* __restrict__ b,
                                                bf16* __restrict__ ef2) {
  int t = threadIdx.x;
  int e = blockIdx.x * 8 + (t >> 5);
  int c8 = (t & 31) * 8;
  size_t base = (size_t)e * 256 + c8;
  short8 out = {};
  if (e < NEDGES) {
    int node = (c8 < 128) ? ei[e] : ei[NEDGES + e];
    short8 yv = *(const short8*)&ef2[base];
    short8 res = *(const short8*)&xrb[(size_t)node * 128 + (c8 & 127)];
#pragma unroll
    for (int j = 0; j < 8; ++j) {
      int c = c8 + j;
      float m = stats[c] * (1.f / NEDGES);
      float var = stats[256 + c] * (1.f / NEDGES) - m * m;
      float rstd = rsqrtf(var + BN_EPS);
      float v = (b2f(yv[j]) - m) * rstd * w[c] + b[c] + b2f(res[j]);
      out[j] = f2b(fmaxf(v, 0.f));
    }
  }
  *(short8*)&ef2[base] = out;
}

// y2 <- relu(bn4(y2) + ef2), in place, 8 elems/thread
__global__ void ef3_inplace(bf16* __restrict__ y2, const bf16* __restrict__ ef2,
                            const float* __restrict__ stats, const float* __restrict__ w,
                            const float* __restrict__ b) {
  int t = blockIdx.x * 256 + threadIdx.x;
  size_t base = (size_t)t * 8;
  int c0 = (int)(base & 255);
  short8 yv = *(const short8*)(y2 + base);
  short8 ev = *(const short8*)(ef2 + base);
  short8 out;
#pragma unroll
  for (int j = 0; j < 8; ++j) {
    int c = c0 + j;
    float m = stats[c] * (1.f / NEDGES);
    float var = stats[256 + c] * (1.f / NEDGES) - m * m;
    float rstd = rsqrtf(var + BN_EPS);
    float v = fmaxf((b2f(yv[j]) - m) * rstd * w[c] + b[c] + b2f(ev[j]), 0.f);
    out[j] = f2b(v);
  }
  *(short8*)(y2 + base) = out;
}

// ---------------- launch ----------------

extern "C" void kernel_launch(void* const* d_in, const int* in_sizes, int n_in,
                              void* d_out, int out_size, void* d_ws, size_t ws_size,
                              hipStream_t stream) {
  const float* x    = (const float*)d_in[0];
  const int*   ei   = (const int*)d_in[1];
  const float* w0   = (const float*)d_in[2];
  const float* ats0 = (const float*)d_in[4];
  const float* atd0 = (const float*)d_in[5];
  const float* bn1w = (const float*)d_in[6];
  const float* bn1b = (const float*)d_in[7];
  const float* w2   = (const float*)d_in[8];
  const float* ats1 = (const float*)d_in[10];
  const float* atd1 = (const float*)d_in[11];
  const float* bn2w = (const float*)d_in[12];
  const float* bn2b = (const float*)d_in[13];
  const float* w4   = (const float*)d_in[14];
  const float* bn3w = (const float*)d_in[16];
  const float* bn3b = (const float*)d_in[17];
  const float* w6   = (const float*)d_in[18];
  const float* bn4w = (const float*)d_in[20];
  const float* bn4b = (const float*)d_in[21];
  const float* w8   = (const float*)d_in[22];
  const float* b8   = (const float*)d_in[23];

  // ---- explicit workspace layout (peak ~307.8 MB) ----
  const size_t REG = 153616384;  // EDGE_PAD*256*2
  char* ws = (char*)d_ws;
  bf16*  ef2b = (bf16*)ws;          // y1 -> ef2 (in place) -> ef3 residual
  char*  R    = ws + REG;
  float* hbuf  = (float*)(R);
  bf16*  xb    = (bf16*)(R + 61603840);
  bf16*  x1b   = (bf16*)(R + 65454080);
  bf16*  xrb   = (bf16*)(R + 73154560);
  float* a_s   = (float*)(R + 80855040);
  float* a_d   = (float*)(R + 81335040);
  u32*   amaxU = (u32*)  (R + 81815040);
  float* denom = (float*)(R + 82295040);
  float* alphaE= (float*)(R + 82775040);
  float* agg   = (float*)(R + 87575040);
  float* PQ    = hbuf;
  bf16*  y2b   = (bf16*)R;
  char*  S     = ws + 2 * REG;
  bf16*  w0b   = (bf16*)(S);
  bf16*  w2b   = (bf16*)(S + 65536);
  bf16*  w45b  = (bf16*)(S + 196608);
  bf16*  w6b   = (bf16*)(S + 327680);
  bf16*  w8pb  = (bf16*)(S + 458752);
  float* stats1= (float*)(S + 524288);
  float* stats2= (float*)(S + 526336);
  const size_t needed = 2 * REG + 528384;
  if (ws_size < needed) {
    fillpat<<<(out_size + 255) / 256, 256, 0, stream>>>((u32*)d_out, 0x7F7F7F7Fu, out_size);
    return;
  }

  // ---- convert inputs/weights to bf16 (padded) ----
  cvt_bf16_pad<<<(NODE_PAD * 64 + 255) / 256, 256, 0, stream>>>(x, xb, NNODES, NODE_PAD * 64, 64);
  cvt_bf16_pad<<<(512 * 64 + 255) / 256, 256, 0, stream>>>(w0, w0b, 512, 512 * 64, 64);
  cvt_bf16_pad<<<(512 * 128 + 255) / 256, 256, 0, stream>>>(w2, w2b, 512, 512 * 128, 128);
  cvt_w45<<<(512 * 128 + 255) / 256, 256, 0, stream>>>(w4, w45b);
  cvt_bf16_pad<<<(256 * 256 + 255) / 256, 256, 0, stream>>>(w6, w6b, 256, 256 * 256, 256);
  cvt_bf16_pad<<<(128 * 256 + 255) / 256, 256, 0, stream>>>(w8, w8pb, 86, 128 * 256, 256);

  const int etb = (NEDGES * 4 + 255) / 256;

  // ---- GAT layer 1 ----
  gemm_bt<false, false><<<dim3(NODE_PAD / 128, 4), 256, 0, stream>>>(xb, w0b, hbuf, 64, 512, NODE_PAD, 512, nullptr, nullptr);
  att_reduce<<<NNODES, 256, 0, stream>>>(hbuf, ats0, atd0, a_s, a_d);
  zfill<<<(240000 + 255) / 256, 256, 0, stream>>>(amaxU, 240000);
  zfill<<<(3840000 + 255) / 256, 256, 0, stream>>>((u32*)agg, 3840000);
  edge_alpha_max<<<etb, 256, 0, stream>>>(ei, a_s, a_d, alphaE, amaxU);
  edge_exp_sum<<<etb, 256, 0, stream>>>(ei, alphaE, amaxU, denom);
  edge_scatter<<<NEDGES / 2, 256, 0, stream>>>(ei, hbuf, alphaE, denom, agg);
  zfill<<<1, 256, 0, stream>>>((u32*)stats1, 256);
  col_stats128<<<(NNODES + 63) / 64, 256, 0, stream>>>(agg, stats1, NNODES);
  bn_relu_node<<<NODE_PAD * 128 / 256, 256, 0, stream>>>(agg, stats1, bn1w, bn1b, x1b);

  // ---- GAT layer 2 ----
  gemm_bt<false, false><<<dim3(NODE_PAD / 128, 4), 256, 0, stream>>>(x1b, w2b, hbuf, 128, 512, NODE_PAD, 512, nullptr, nullptr);
  att_reduce<<<NNODES, 256, 0, stream>>>(hbuf, ats1, atd1, a_s, a_d);
  zfill<<<(240000 + 255) / 256, 256, 0, stream>>>(amaxU, 240000);
  zfill<<<(3840000 + 255) / 256, 256, 0, stream>>>((u32*)agg, 3840000);
  edge_alpha_max<<<etb, 256, 0, stream>>>(ei, a_s, a_d, alphaE, amaxU);
  edge_exp_sum<<<etb, 256, 0, stream>>>(ei, alphaE, amaxU, denom);
  edge_scatter<<<NEDGES / 2, 256, 0, stream>>>(ei, hbuf, alphaE, denom, agg);
  zfill<<<1, 256, 0, stream>>>((u32*)stats1, 256);
  col_stats128<<<(NNODES + 63) / 64, 256, 0, stream>>>(agg, stats1, NNODES);
  bn_res_relu_node<<<NODE_PAD * 128 / 256, 256, 0, stream>>>(agg, stats1, bn2w, bn2b, x1b, xrb);

  // ---- edge MLP ----
  gemm_bt<false, false><<<dim3(NODE_PAD / 128, 4), 256, 0, stream>>>(xrb, w45b, PQ, 128, 512, NODE_PAD, 512, nullptr, nullptr);
  zfill<<<2, 256, 0, stream>>>((u32*)stats1, 512);
  e_stats_mat<<<(NEDGES + 127) / 128, 256, 0, stream>>>(ei, PQ, ef2b, stats1);
  ef2_norm<<<EDGE_PAD / 8, 256, 0, stream>>>(ei, xrb, stats1, bn3w, bn3b, ef2b);
  zfill<<<2, 256, 0, stream>>>((u32*)stats2, 512);
  gemm_bt<true, true><<<dim3(EDGE_PAD / 128, 2), 256, 0, stream>>>(ef2b, w6b, y2b, 256, 256, EDGE_PAD, 256, nullptr, stats2);
  ef3_inplace<<<NEDGES / 8, 256, 0, stream>>>(y2b, ef2b, stats2, bn4w, bn4b);
  gemm_bt<false, false><<<dim3(EDGE_PAD / 128, 1), 256, 0, stream>>>(y2b, w8pb, (float*)d_out, 256, 86, NEDGES, 86, b8, nullptr);
}

// Round 5
// 1031.210 us; speedup vs baseline: 1.3949x; 1.1739x over previous
//
#include <hip/hip_runtime.h>
#include <hip/hip_bf16.h>
#include <stdint.h>

typedef __hip_bfloat16 bf16;
typedef unsigned int u32;
typedef __attribute__((ext_vector_type(8))) short short8;
typedef __attribute__((ext_vector_type(4))) short short4v;
typedef __attribute__((ext_vector_type(4))) float f32x4;

#define NNODES 30000
#define NEDGES 300000
#define NODE_PAD 30080   // 235*128
#define EDGE_PAD 300032  // 2344*128
#define NEG_SLOPE 0.2f
#define BN_EPS 1e-5f

__device__ __forceinline__ float b2f(short s) {
  u32 u = ((u32)(unsigned short)s) << 16;
  return __uint_as_float(u);
}
__device__ __forceinline__ short f2b(float f) {
  bf16 h = __float2bfloat16(f);
  return *(short*)&h;
}

__device__ __forceinline__ void gload16(const void* g, void* l) {
  __builtin_amdgcn_global_load_lds(
      (__attribute__((address_space(1))) unsigned int*)(uintptr_t)g,
      (__attribute__((address_space(3))) unsigned int*)(uintptr_t)l, 16, 0, 0);
}

// ---------------- tiny utility kernels ----------------

__global__ void zfill(u32* __restrict__ p, int n) {
  int i = blockIdx.x * 256 + threadIdx.x;
  if (i < n) p[i] = 0u;
}

__global__ void fillpat(u32* __restrict__ p, u32 v, int n) {
  int i = blockIdx.x * 256 + threadIdx.x;
  if (i < n) p[i] = v;
}

__global__ void cvt_bf16_pad(const float* __restrict__ src, bf16* __restrict__ dst,
                             int rows_valid, int total, int cols) {
  int i = blockIdx.x * 256 + threadIdx.x;
  if (i >= total) return;
  int r = i / cols;
  float v = (r < rows_valid) ? src[i] : 0.f;
  dst[i] = __float2bfloat16(v);
}

// w45[n][k] = n<256 ? w4[n][k] : w4[n-256][128+k]
__global__ void cvt_w45(const float* __restrict__ w4, bf16* __restrict__ w45b) {
  int i = blockIdx.x * 256 + threadIdx.x;
  if (i >= 512 * 128) return;
  int n = i >> 7, k = i & 127;
  float v = (n < 256) ? w4[n * 256 + k] : w4[(n - 256) * 256 + 128 + k];
  w45b[i] = __float2bfloat16(v);
}

// ---------------- GEMM: C[M,N] = A[M,K] @ B[N,K]^T  (bf16 in) ----------------
template <bool BF16OUT, bool STATS>
__global__ __launch_bounds__(256) void gemm_bt(
    const bf16* __restrict__ A, const bf16* __restrict__ B, void* __restrict__ Cout,
    int K, int ldc, int Mvalid, int Nvalid, const float* __restrict__ bias,
    float* __restrict__ statsOut) {
  __shared__ __align__(16) short sm[2][128 * 64];
  const int tid = threadIdx.x;
  const int lane = tid & 63;
  const int wid = tid >> 6;
  const int wr = wid >> 1, wc = wid & 1;
  const size_t arow0 = (size_t)blockIdx.x * 128;
  const size_t brow0 = (size_t)blockIdx.y * 128;
  f32x4 acc[4][4] = {};
  const int nk = K >> 6;
  for (int kt = 0; kt < nk; ++kt) {
    const int kbase = kt * 64;
#pragma unroll
    for (int i = 0; i < 4; ++i) {
      int s = i * 256 + tid;
      int row = s >> 3;
      int c8l = (s & 7) ^ (row & 7);
      gload16(A + (arow0 + row) * K + kbase + c8l * 8, &sm[0][s * 8]);
      gload16(B + (brow0 + row) * K + kbase + c8l * 8, &sm[1][s * 8]);
    }
    __syncthreads();
#pragma unroll
    for (int ks = 0; ks < 2; ++ks) {
      short8 af[4], bfr[4];
      const int cg = ks * 4 + (lane >> 4);
#pragma unroll
      for (int m = 0; m < 4; ++m) {
        int row = wr * 64 + m * 16 + (lane & 15);
        af[m] = *(const short8*)&sm[0][row * 64 + ((cg ^ (row & 7)) << 3)];
      }
#pragma unroll
      for (int n = 0; n < 4; ++n) {
        int row = wc * 64 + n * 16 + (lane & 15);
        bfr[n] = *(const short8*)&sm[1][row * 64 + ((cg ^ (row & 7)) << 3)];
      }
#pragma unroll
      for (int m = 0; m < 4; ++m)
#pragma unroll
        for (int n = 0; n < 4; ++n)
          acc[m][n] = __builtin_amdgcn_mfma_f32_16x16x32_bf16(af[m], bfr[n], acc[m][n], 0, 0, 0);
    }
    __syncthreads();
  }
  if constexpr (STATS) {
    float* smS = (float*)&sm[0][0];
    float* smQ = smS + 256;
#pragma unroll
    for (int n = 0; n < 4; ++n) {
      float s = 0.f, q = 0.f;
#pragma unroll
      for (int m = 0; m < 4; ++m)
#pragma unroll
        for (int r = 0; r < 4; ++r) {
          float v = acc[m][n][r];
          s += v;
          q += v * v;
        }
      s += __shfl_xor(s, 16); s += __shfl_xor(s, 32);
      q += __shfl_xor(q, 16); q += __shfl_xor(q, 32);
      if (lane < 16) {
        int col = wc * 64 + n * 16 + lane;
        smS[wr * 128 + col] = s;
        smQ[wr * 128 + col] = q;
      }
    }
    __syncthreads();
    if (tid < 128) {
      atomicAdd(&statsOut[brow0 + tid], smS[tid] + smS[128 + tid]);
      atomicAdd(&statsOut[256 + brow0 + tid], smQ[tid] + smQ[128 + tid]);
    }
  }
  const int rbase = (int)arow0 + wr * 64 + (lane >> 4) * 4;
  const int cbase = (int)brow0 + wc * 64 + (lane & 15);
#pragma unroll
  for (int m = 0; m < 4; ++m) {
#pragma unroll
    for (int n = 0; n < 4; ++n) {
      int col = cbase + n * 16;
      if (col >= Nvalid) continue;
      float badd = bias ? bias[col] : 0.f;
#pragma unroll
      for (int r = 0; r < 4; ++r) {
        int row = rbase + m * 16 + r;
        if (row < Mvalid) {
          if constexpr (BF16OUT)
            ((bf16*)Cout)[(size_t)row * ldc + col] = __float2bfloat16(acc[m][n][r] + badd);
          else
            ((float*)Cout)[(size_t)row * ldc + col] = acc[m][n][r] + badd;
        }
      }
    }
  }
}

// ---------------- GAT pieces (h is bf16) ----------------

__global__ __launch_bounds__(256) void att_reduce(
    const bf16* __restrict__ h, const float* __restrict__ ats, const float* __restrict__ atd,
    float* __restrict__ a_s, float* __restrict__ a_d) {
  int n = blockIdx.x;
  int lane = threadIdx.x & 63;
  int hd = threadIdx.x >> 6;
  const bf16* hp = h + (size_t)n * 512 + hd * 128;
  const float* sw = ats + hd * 128;
  const float* dw = atd + hd * 128;
  float h1 = __bfloat162float(hp[lane]), h2 = __bfloat162float(hp[lane + 64]);
  float s = h1 * sw[lane] + h2 * sw[lane + 64];
  float d = h1 * dw[lane] + h2 * dw[lane + 64];
#pragma unroll
  for (int off = 32; off > 0; off >>= 1) {
    s += __shfl_down(s, off);
    d += __shfl_down(d, off);
  }
  if (lane == 0) {
    a_s[n * 4 + hd] = s;
    a_d[n * 4 + hd] = d;
  }
}

__global__ void edge_alpha_max(const int* __restrict__ ei, const float* __restrict__ a_s,
                               const float* __restrict__ a_d, float* __restrict__ alphaE,
                               u32* __restrict__ amaxU) {
  int t = blockIdx.x * 256 + threadIdx.x;
  if (t >= NEDGES * 4) return;
  int e = t >> 2, h = t & 3;
  int s = ei[e], d = ei[NEDGES + e];
  float a = a_s[s * 4 + h] + a_d[d * 4 + h];
  a = (a > 0.f) ? a : NEG_SLOPE * a;
  alphaE[t] = a;
  u32 bits = __float_as_uint(a);
  u32 key = bits ^ (((int)bits < 0) ? 0xFFFFFFFFu : 0x80000000u);
  atomicMax(&amaxU[d * 4 + h], key);
}

__global__ void edge_exp_sum(const int* __restrict__ ei, float* __restrict__ alphaE,
                             const u32* __restrict__ amaxU, float* __restrict__ denom) {
  int t = blockIdx.x * 256 + threadIdx.x;
  if (t >= NEDGES * 4) return;
  int e = t >> 2, h = t & 3;
  int d = ei[NEDGES + e];
  u32 k = amaxU[d * 4 + h];
  u32 bits = (k & 0x80000000u) ? (k ^ 0x80000000u) : ~k;
  float am = __uint_as_float(bits);
  float ev = __expf(alphaE[t] - am);
  alphaE[t] = ev;
  atomicAdd(&denom[d * 4 + h], ev);
}

__global__ void edge_scatter(const int* __restrict__ ei, const bf16* __restrict__ hbuf,
                             const float* __restrict__ evals, const float* __restrict__ denom,
                             float* __restrict__ agg) {
  int e = blockIdx.x * 2 + (threadIdx.x >> 7);
  int d = threadIdx.x & 127;
  int s = ei[e], dd = ei[NEDGES + e];
  const short* hp = (const short*)hbuf + (size_t)s * 512 + d;
  float sum = 0.f;
#pragma unroll
  for (int h = 0; h < 4; ++h) {
    float coef = evals[e * 4 + h] / denom[dd * 4 + h];
    sum += b2f(hp[h * 128]) * coef;
  }
  atomicAdd(&agg[dd * 128 + d], sum * 0.25f);
}

// ---------------- BatchNorm pieces ----------------

__global__ __launch_bounds__(256) void col_stats128(const float* __restrict__ X,
                                                    float* __restrict__ stats, int rows) {
  __shared__ float smS[8][128], smQ[8][128];
  int t = threadIdx.x;
  int sub = t >> 5;
  int c4 = (t & 31) * 4;
  int rend = blockIdx.x * 64 + 64;
  if (rend > rows) rend = rows;
  f32x4 s = {}, q = {};
  for (int r = blockIdx.x * 64 + sub; r < rend; r += 8) {
    f32x4 v = *(const f32x4*)&X[(size_t)r * 128 + c4];
    s += v;
    q += v * v;
  }
  *(f32x4*)&smS[sub][c4] = s;
  *(f32x4*)&smQ[sub][c4] = q;
  __syncthreads();
  if (t < 128) {
    float ts = 0.f, tq = 0.f;
#pragma unroll
    for (int g = 0; g < 8; ++g) { ts += smS[g][t]; tq += smQ[g][t]; }
    atomicAdd(&stats[t], ts);
    atomicAdd(&stats[128 + t], tq);
  }
}

__global__ void bn_relu_node(const float* __restrict__ agg, const float* __restrict__ stats,
                             const float* __restrict__ w, const float* __restrict__ b,
                             bf16* __restrict__ xout) {
  int i = blockIdx.x * 256 + threadIdx.x;
  if (i >= NODE_PAD * 128) return;
  int r = i >> 7, c = i & 127;
  float v = 0.f;
  if (r < NNODES) {
    float m = stats[c] * (1.f / NNODES);
    float var = stats[128 + c] * (1.f / NNODES) - m * m;
    float rstd = rsqrtf(var + BN_EPS);
    v = fmaxf((agg[i] - m) * rstd * w[c] + b[c], 0.f);
  }
  xout[i] = __float2bfloat16(v);
}

__global__ void bn_res_relu_node(const float* __restrict__ agg, const float* __restrict__ stats,
                                 const float* __restrict__ w, const float* __restrict__ b,
                                 const bf16* __restrict__ x1b, bf16* __restrict__ xrb) {
  int i = blockIdx.x * 256 + threadIdx.x;
  if (i >= NODE_PAD * 128) return;
  int r = i >> 7, c = i & 127;
  float v = 0.f;
  if (r < NNODES) {
    float m = stats[c] * (1.f / NNODES);
    float var = stats[128 + c] * (1.f / NNODES) - m * m;
    float rstd = rsqrtf(var + BN_EPS);
    v = fmaxf((agg[i] - m) * rstd * w[c] + b[c] + __bfloat162float(x1b[i]), 0.f);
  }
  xrb[i] = __float2bfloat16(v);
}

// ---------------- edge-MLP head ----------------
// Pass 1: gather y1 = P[src]+Q[dst] ONCE (PQ bf16); write y1 bf16 + col stats.
// 128 edges/block = 8 subgroups x 16 edges, unroll 4 -> 8 short8 gathers in flight.
__device__ __forceinline__ void accum_edge(short8 pa, short8 qa, bf16* __restrict__ y1out,
                                           size_t obase, f32x4& s0, f32x4& s1,
                                           f32x4& q0, f32x4& q1) {
  short8 o;
  float v[8];
#pragma unroll
  for (int j = 0; j < 8; ++j) {
    v[j] = b2f(pa[j]) + b2f(qa[j]);
    o[j] = f2b(v[j]);
  }
  *(short8*)(y1out + obase) = o;
  s0[0] += v[0]; s0[1] += v[1]; s0[2] += v[2]; s0[3] += v[3];
  s1[0] += v[4]; s1[1] += v[5]; s1[2] += v[6]; s1[3] += v[7];
  q0[0] += v[0] * v[0]; q0[1] += v[1] * v[1]; q0[2] += v[2] * v[2]; q0[3] += v[3] * v[3];
  q1[0] += v[4] * v[4]; q1[1] += v[5] * v[5]; q1[2] += v[6] * v[6]; q1[3] += v[7] * v[7];
}

__global__ __launch_bounds__(256) void e_stats_mat(const int* __restrict__ ei,
                                                   const bf16* __restrict__ PQ,
                                                   bf16* __restrict__ y1out,
                                                   float* __restrict__ stats) {
  __shared__ float smS[8][256], smQ[8][256];
  int t = threadIdx.x;
  int sub = t >> 5;
  int c8 = (t & 31) * 8;
  int ebase = blockIdx.x * 128 + sub * 16;
  f32x4 s0 = {}, s1 = {}, q0 = {}, q1 = {};
#pragma unroll 1
  for (int i = 0; i < 16; i += 4) {
    int e = ebase + i;
    if (e + 3 < NEDGES) {
      int4 sn = *(const int4*)&ei[e];
      int4 dn = *(const int4*)&ei[NEDGES + e];
      short8 p0 = *(const short8*)&PQ[(size_t)sn.x * 512 + c8];
      short8 p1 = *(const short8*)&PQ[(size_t)sn.y * 512 + c8];
      short8 p2 = *(const short8*)&PQ[(size_t)sn.z * 512 + c8];
      short8 p3 = *(const short8*)&PQ[(size_t)sn.w * 512 + c8];
      short8 r0 = *(const short8*)&PQ[(size_t)dn.x * 512 + 256 + c8];
      short8 r1 = *(const short8*)&PQ[(size_t)dn.y * 512 + 256 + c8];
      short8 r2 = *(const short8*)&PQ[(size_t)dn.z * 512 + 256 + c8];
      short8 r3 = *(const short8*)&PQ[(size_t)dn.w * 512 + 256 + c8];
      accum_edge(p0, r0, y1out, (size_t)e * 256 + c8, s0, s1, q0, q1);
      accum_edge(p1, r1, y1out, (size_t)(e + 1) * 256 + c8, s0, s1, q0, q1);
      accum_edge(p2, r2, y1out, (size_t)(e + 2) * 256 + c8, s0, s1, q0, q1);
      accum_edge(p3, r3, y1out, (size_t)(e + 3) * 256 + c8, s0, s1, q0, q1);
    } else {
      for (int j = 0; j < 4; ++j) {
        int ej = e + j;
        if (ej >= NEDGES) break;
        int sn = ei[ej], dn = ei[NEDGES + ej];
        short8 p = *(const short8*)&PQ[(size_t)sn * 512 + c8];
        short8 r = *(const short8*)&PQ[(size_t)dn * 512 + 256 + c8];
        accum_edge(p, r, y1out, (size_t)ej * 256 + c8, s0, s1, q0, q1);
      }
    }
  }
  *(f32x4*)&smS[sub][c8] = s0;
  *(f32x4*)&smS[sub][c8 + 4] = s1;
  *(f32x4*)&smQ[sub][c8] = q0;
  *(f32x4*)&smQ[sub][c8 + 4] = q1;
  __syncthreads();
  float ts = 0.f, tq = 0.f;
#pragma unroll
  for (int g = 0; g < 8; ++g) { ts += smS[g][t]; tq += smQ[g][t]; }
  atomicAdd(&stats[t], ts);
  atomicAdd(&stats[256 + t], tq);
}

// Pass 2: ef2 = relu(bn3(y1) + xr[src|dst]) IN PLACE on the y1 buffer.
__global__ __launch_bounds__(256) void ef2_norm(const int* __restrict__ ei,
                                                const bf16* __restrict__ xrb,
                                                const float* __restrict__ stats,
                                                const float* __restrict__ w,
                                                const float* __restrict__ b,
                                                bf16* __restrict__ ef2) {
  int t = threadIdx.x;
  int e = blockIdx.x * 8 + (t >> 5);
  int c8 = (t & 31) * 8;
  size_t base = (size_t)e * 256 + c8;
  short8 out = {};
  if (e < NEDGES) {
    int node = (c8 < 128) ? ei[e] : ei[NEDGES + e];
    short8 yv = *(const short8*)&ef2[base];
    short8 res = *(const short8*)&xrb[(size_t)node * 128 + (c8 & 127)];
#pragma unroll
    for (int j = 0; j < 8; ++j) {
      int c = c8 + j;
      float m = stats[c] * (1.f / NEDGES);
      float var = stats[256 + c] * (1.f / NEDGES) - m * m;
      float rstd = rsqrtf(var + BN_EPS);
      float v = (b2f(yv[j]) - m) * rstd * w[c] + b[c] + b2f(res[j]);
      out[j] = f2b(fmaxf(v, 0.f));
    }
  }
  *(short8*)&ef2[base] = out;
}

// y2 <- relu(bn4(y2) + ef2), in place, 8 elems/thread
__global__ void ef3_inplace(bf16* __restrict__ y2, const bf16* __restrict__ ef2,
                            const float* __restrict__ stats, const float* __restrict__ w,
                            const float* __restrict__ b) {
  int t = blockIdx.x * 256 + threadIdx.x;
  size_t base = (size_t)t * 8;
  int c0 = (int)(base & 255);
  short8 yv = *(const short8*)(y2 + base);
  short8 ev = *(const short8*)(ef2 + base);
  short8 out;
#pragma unroll
  for (int j = 0; j < 8; ++j) {
    int c = c0 + j;
    float m = stats[c] * (1.f / NEDGES);
    float var = stats[256 + c] * (1.f / NEDGES) - m * m;
    float rstd = rsqrtf(var + BN_EPS);
    float v = fmaxf((b2f(yv[j]) - m) * rstd * w[c] + b[c] + b2f(ev[j]), 0.f);
    out[j] = f2b(v);
  }
  *(short8*)(y2 + base) = out;
}

// ---------------- launch ----------------

extern "C" void kernel_launch(void* const* d_in, const int* in_sizes, int n_in,
                              void* d_out, int out_size, void* d_ws, size_t ws_size,
                              hipStream_t stream) {
  const float* x    = (const float*)d_in[0];
  const int*   ei   = (const int*)d_in[1];
  const float* w0   = (const float*)d_in[2];
  const float* ats0 = (const float*)d_in[4];
  const float* atd0 = (const float*)d_in[5];
  const float* bn1w = (const float*)d_in[6];
  const float* bn1b = (const float*)d_in[7];
  const float* w2   = (const float*)d_in[8];
  const float* ats1 = (const float*)d_in[10];
  const float* atd1 = (const float*)d_in[11];
  const float* bn2w = (const float*)d_in[12];
  const float* bn2b = (const float*)d_in[13];
  const float* w4   = (const float*)d_in[14];
  const float* bn3w = (const float*)d_in[16];
  const float* bn3b = (const float*)d_in[17];
  const float* w6   = (const float*)d_in[18];
  const float* bn4w = (const float*)d_in[20];
  const float* bn4b = (const float*)d_in[21];
  const float* w8   = (const float*)d_in[22];
  const float* b8   = (const float*)d_in[23];

  // ---- explicit workspace layout (peak ~307.8 MB) ----
  const size_t REG = 153616384;  // EDGE_PAD*256*2
  char* ws = (char*)d_ws;
  bf16*  ef2b = (bf16*)ws;          // y1 -> ef2 (in place) -> ef3 residual
  char*  R    = ws + REG;
  bf16*  hb    = (bf16*)(R);                  // node GEMM out (bf16) / later PQ
  bf16*  xb    = (bf16*)(R + 61603840);
  bf16*  x1b   = (bf16*)(R + 65454080);
  bf16*  xrb   = (bf16*)(R + 73154560);
  float* a_s   = (float*)(R + 80855040);
  float* a_d   = (float*)(R + 81335040);
  u32*   amaxU = (u32*)  (R + 81815040);
  float* denom = (float*)(R + 82295040);
  float* alphaE= (float*)(R + 82775040);
  float* agg   = (float*)(R + 87575040);
  bf16*  PQ    = hb;
  bf16*  y2b   = (bf16*)R;                    // GEMM2 out, overwrites node stuff
  char*  S     = ws + 2 * REG;
  bf16*  w0b   = (bf16*)(S);
  bf16*  w2b   = (bf16*)(S + 65536);
  bf16*  w45b  = (bf16*)(S + 196608);
  bf16*  w6b   = (bf16*)(S + 327680);
  bf16*  w8pb  = (bf16*)(S + 458752);
  float* stats1= (float*)(S + 524288);
  float* stats2= (float*)(S + 526336);
  const size_t needed = 2 * REG + 528384;
  if (ws_size < needed) {
    fillpat<<<(out_size + 255) / 256, 256, 0, stream>>>((u32*)d_out, 0x7F7F7F7Fu, out_size);
    return;
  }

  // ---- convert inputs/weights to bf16 (padded) ----
  cvt_bf16_pad<<<(NODE_PAD * 64 + 255) / 256, 256, 0, stream>>>(x, xb, NNODES, NODE_PAD * 64, 64);
  cvt_bf16_pad<<<(512 * 64 + 255) / 256, 256, 0, stream>>>(w0, w0b, 512, 512 * 64, 64);
  cvt_bf16_pad<<<(512 * 128 + 255) / 256, 256, 0, stream>>>(w2, w2b, 512, 512 * 128, 128);
  cvt_w45<<<(512 * 128 + 255) / 256, 256, 0, stream>>>(w4, w45b);
  cvt_bf16_pad<<<(256 * 256 + 255) / 256, 256, 0, stream>>>(w6, w6b, 256, 256 * 256, 256);
  cvt_bf16_pad<<<(128 * 256 + 255) / 256, 256, 0, stream>>>(w8, w8pb, 86, 128 * 256, 256);

  const int etb = (NEDGES * 4 + 255) / 256;

  // ---- GAT layer 1 ----
  gemm_bt<true, false><<<dim3(NODE_PAD / 128, 4), 256, 0, stream>>>(xb, w0b, hb, 64, 512, NODE_PAD, 512, nullptr, nullptr);
  att_reduce<<<NNODES, 256, 0, stream>>>(hb, ats0, atd0, a_s, a_d);
  zfill<<<(240000 + 255) / 256, 256, 0, stream>>>(amaxU, 240000);
  zfill<<<(3840000 + 255) / 256, 256, 0, stream>>>((u32*)agg, 3840000);
  edge_alpha_max<<<etb, 256, 0, stream>>>(ei, a_s, a_d, alphaE, amaxU);
  edge_exp_sum<<<etb, 256, 0, stream>>>(ei, alphaE, amaxU, denom);
  edge_scatter<<<NEDGES / 2, 256, 0, stream>>>(ei, hb, alphaE, denom, agg);
  zfill<<<1, 256, 0, stream>>>((u32*)stats1, 256);
  col_stats128<<<(NNODES + 63) / 64, 256, 0, stream>>>(agg, stats1, NNODES);
  bn_relu_node<<<NODE_PAD * 128 / 256, 256, 0, stream>>>(agg, stats1, bn1w, bn1b, x1b);

  // ---- GAT layer 2 ----
  gemm_bt<true, false><<<dim3(NODE_PAD / 128, 4), 256, 0, stream>>>(x1b, w2b, hb, 128, 512, NODE_PAD, 512, nullptr, nullptr);
  att_reduce<<<NNODES, 256, 0, stream>>>(hb, ats1, atd1, a_s, a_d);
  zfill<<<(240000 + 255) / 256, 256, 0, stream>>>(amaxU, 240000);
  zfill<<<(3840000 + 255) / 256, 256, 0, stream>>>((u32*)agg, 3840000);
  edge_alpha_max<<<etb, 256, 0, stream>>>(ei, a_s, a_d, alphaE, amaxU);
  edge_exp_sum<<<etb, 256, 0, stream>>>(ei, alphaE, amaxU, denom);
  edge_scatter<<<NEDGES / 2, 256, 0, stream>>>(ei, hb, alphaE, denom, agg);
  zfill<<<1, 256, 0, stream>>>((u32*)stats1, 256);
  col_stats128<<<(NNODES + 63) / 64, 256, 0, stream>>>(agg, stats1, NNODES);
  bn_res_relu_node<<<NODE_PAD * 128 / 256, 256, 0, stream>>>(agg, stats1, bn2w, bn2b, x1b, xrb);

  // ---- edge MLP ----
  gemm_bt<true, false><<<dim3(NODE_PAD / 128, 4), 256, 0, stream>>>(xrb, w45b, PQ, 128, 512, NODE_PAD, 512, nullptr, nullptr);
  zfill<<<2, 256, 0, stream>>>((u32*)stats1, 512);
  e_stats_mat<<<(NEDGES + 127) / 128, 256, 0, stream>>>(ei, PQ, ef2b, stats1);
  ef2_norm<<<EDGE_PAD / 8, 256, 0, stream>>>(ei, xrb, stats1, bn3w, bn3b, ef2b);
  zfill<<<2, 256, 0, stream>>>((u32*)stats2, 512);
  gemm_bt<true, true><<<dim3(EDGE_PAD / 128, 2), 256, 0, stream>>>(ef2b, w6b, y2b, 256, 256, EDGE_PAD, 256, nullptr, stats2);
  ef3_inplace<<<NEDGES / 8, 256, 0, stream>>>(y2b, ef2b, stats2, bn4w, bn4b);
  gemm_bt<false, false><<<dim3(EDGE_PAD / 128, 1), 256, 0, stream>>>(y2b, w8pb, (float*)d_out, 256, 86, NEDGES, 86, b8, nullptr);
}

// Round 6
// 966.193 us; speedup vs baseline: 1.4888x; 1.0673x over previous
//
#include <hip/hip_runtime.h>
#include <hip/hip_bf16.h>
#include <stdint.h>

typedef __hip_bfloat16 bf16;
typedef unsigned int u32;
typedef __attribute__((ext_vector_type(8))) short short8;
typedef __attribute__((ext_vector_type(4))) float f32x4;

#define NNODES 30000
#define NEDGES 300000
#define NODE_PAD 30080   // 235*128
#define EDGE_PAD 300032  // 2344*128
#define NEG_SLOPE 0.2f
#define BN_EPS 1e-5f

__device__ __forceinline__ float b2f(short s) {
  u32 u = ((u32)(unsigned short)s) << 16;
  return __uint_as_float(u);
}
__device__ __forceinline__ short f2b(float f) {
  bf16 h = __float2bfloat16(f);
  return *(short*)&h;
}

__device__ __forceinline__ void gload16(const void* g, void* l) {
  __builtin_amdgcn_global_load_lds(
      (__attribute__((address_space(1))) unsigned int*)(uintptr_t)g,
      (__attribute__((address_space(3))) unsigned int*)(uintptr_t)l, 16, 0, 0);
}

// ---------------- tiny utility kernels ----------------

__global__ void zfill(u32* __restrict__ p, int n) {
  int i = blockIdx.x * 256 + threadIdx.x;
  if (i < n) p[i] = 0u;
}

__global__ void fillpat(u32* __restrict__ p, u32 v, int n) {
  int i = blockIdx.x * 256 + threadIdx.x;
  if (i < n) p[i] = v;
}

__global__ void cvt_bf16_pad(const float* __restrict__ src, bf16* __restrict__ dst,
                             int rows_valid, int total, int cols) {
  int i = blockIdx.x * 256 + threadIdx.x;
  if (i >= total) return;
  int r = i / cols;
  float v = (r < rows_valid) ? src[i] : 0.f;
  dst[i] = __float2bfloat16(v);
}

// w45[n][k] = n<256 ? w4[n][k] : w4[n-256][128+k]
__global__ void cvt_w45(const float* __restrict__ w4, bf16* __restrict__ w45b) {
  int i = blockIdx.x * 256 + threadIdx.x;
  if (i >= 512 * 128) return;
  int n = i >> 7, k = i & 127;
  float v = (n < 256) ? w4[n * 256 + k] : w4[(n - 256) * 256 + 128 + k];
  w45b[i] = __float2bfloat16(v);
}

// per-column BN coefficients: y_norm = y*sc[c] + sh[c]
__global__ void bn_coef(const float* __restrict__ stats, const float* __restrict__ w,
                        const float* __restrict__ b, int n, float invN,
                        float* __restrict__ sc, float* __restrict__ sh) {
  int c = threadIdx.x;
  if (c >= n) return;
  float m = stats[c] * invN;
  float var = stats[n + c] * invN - m * m;
  float rstd = rsqrtf(var + BN_EPS);
  sc[c] = rstd * w[c];
  sh[c] = b[c] - m * rstd * w[c];
}

// ---------------- GEMM: C[M,N] = A[M,K] @ B[N,K]^T  (bf16 in) ----------------
// 128x128 tile, BK=64, double-buffered LDS with next-tile prefetch issued
// BEFORE compute (T3 minimum 2-phase). XOR swizzle on pre-swizzled global src.
// FUSEA: A := relu(Araw*sc[col] + sh[col] + A2)  (reg-staged, issue-early/write-late)
template <bool BF16OUT, bool STATS, bool FUSEA>
__global__ __launch_bounds__(256) void gemm_bt(
    const bf16* __restrict__ A, const bf16* __restrict__ B, void* __restrict__ Cout,
    int K, int ldc, int Mvalid, int Nvalid, const float* __restrict__ bias,
    float* __restrict__ statsOut, const bf16* __restrict__ A2,
    const float* __restrict__ sc, const float* __restrict__ sh) {
  __shared__ __align__(16) short smA[2][128 * 64];
  __shared__ __align__(16) short smB[2][128 * 64];
  const int tid = threadIdx.x;
  const int lane = tid & 63;
  const int wid = tid >> 6;
  const int wr = wid >> 1, wc = wid & 1;
  const size_t arow0 = (size_t)blockIdx.x * 128;
  const size_t brow0 = (size_t)blockIdx.y * 128;
  f32x4 acc[4][4] = {};
  const int nk = K >> 6;

  int srow[4], scol[4];
#pragma unroll
  for (int i = 0; i < 4; ++i) {
    int s = i * 256 + tid;
    srow[i] = s >> 3;
    scol[i] = ((s & 7) ^ ((s >> 3) & 7)) * 8;
  }

  auto stageB = [&](int buf, int kt) {
#pragma unroll
    for (int i = 0; i < 4; ++i) {
      int s = i * 256 + tid;
      gload16(B + (brow0 + srow[i]) * K + kt * 64 + scol[i], &smB[buf][s * 8]);
    }
  };
  auto stageA_plain = [&](int buf, int kt) {
#pragma unroll
    for (int i = 0; i < 4; ++i) {
      int s = i * 256 + tid;
      gload16(A + (arow0 + srow[i]) * K + kt * 64 + scol[i], &smA[buf][s * 8]);
    }
  };

  short8 yreg[4], ereg[4];
  auto issueA_fused = [&](int kt) {
#pragma unroll
    for (int i = 0; i < 4; ++i) {
      size_t off = (arow0 + srow[i]) * K + kt * 64 + scol[i];
      yreg[i] = *(const short8*)(A + off);
      ereg[i] = *(const short8*)(A2 + off);
    }
  };
  auto writeA_fused = [&](int buf, int kt) {
#pragma unroll
    for (int i = 0; i < 4; ++i) {
      int cb = kt * 64 + scol[i];
      int s = i * 256 + tid;
      f32x4 sc0 = *(const f32x4*)&sc[cb];
      f32x4 sc1 = *(const f32x4*)&sc[cb + 4];
      f32x4 sh0 = *(const f32x4*)&sh[cb];
      f32x4 sh1 = *(const f32x4*)&sh[cb + 4];
      short8 o;
#pragma unroll
      for (int j = 0; j < 4; ++j) {
        o[j] = f2b(fmaxf(b2f(yreg[i][j]) * sc0[j] + sh0[j] + b2f(ereg[i][j]), 0.f));
        o[j + 4] = f2b(fmaxf(b2f(yreg[i][j + 4]) * sc1[j] + sh1[j] + b2f(ereg[i][j + 4]), 0.f));
      }
      *(short8*)&smA[buf][s * 8] = o;
    }
  };

  auto compute = [&](int buf) {
#pragma unroll
    for (int ks = 0; ks < 2; ++ks) {
      short8 af[4], bfr[4];
      const int cg = ks * 4 + (lane >> 4);
#pragma unroll
      for (int m = 0; m < 4; ++m) {
        int row = wr * 64 + m * 16 + (lane & 15);
        af[m] = *(const short8*)&smA[buf][row * 64 + ((cg ^ (row & 7)) << 3)];
      }
#pragma unroll
      for (int n = 0; n < 4; ++n) {
        int row = wc * 64 + n * 16 + (lane & 15);
        bfr[n] = *(const short8*)&smB[buf][row * 64 + ((cg ^ (row & 7)) << 3)];
      }
#pragma unroll
      for (int m = 0; m < 4; ++m)
#pragma unroll
        for (int n = 0; n < 4; ++n)
          acc[m][n] = __builtin_amdgcn_mfma_f32_16x16x32_bf16(af[m], bfr[n], acc[m][n], 0, 0, 0);
    }
  };

  // prologue: stage tile 0 into buf 0
  stageB(0, 0);
  if constexpr (FUSEA) {
    issueA_fused(0);
    writeA_fused(0, 0);
  } else {
    stageA_plain(0, 0);
  }
  __syncthreads();
  int cur = 0;
  for (int kt = 0; kt < nk; ++kt) {
    bool hn = (kt + 1 < nk);
    if (hn) {
      stageB(cur ^ 1, kt + 1);
      if constexpr (FUSEA) issueA_fused(kt + 1);
      else stageA_plain(cur ^ 1, kt + 1);
    }
    compute(cur);
    if constexpr (FUSEA) {
      if (hn) writeA_fused(cur ^ 1, kt + 1);
    }
    __syncthreads();
    cur ^= 1;
  }

  if constexpr (STATS) {
    float* smS = (float*)&smA[0][0];
    float* smQ = smS + 256;
#pragma unroll
    for (int n = 0; n < 4; ++n) {
      float s = 0.f, q = 0.f;
#pragma unroll
      for (int m = 0; m < 4; ++m)
#pragma unroll
        for (int r = 0; r < 4; ++r) {
          float v = acc[m][n][r];
          s += v;
          q += v * v;
        }
      s += __shfl_xor(s, 16); s += __shfl_xor(s, 32);
      q += __shfl_xor(q, 16); q += __shfl_xor(q, 32);
      if (lane < 16) {
        int col = wc * 64 + n * 16 + lane;
        smS[wr * 128 + col] = s;
        smQ[wr * 128 + col] = q;
      }
    }
    __syncthreads();
    if (tid < 128) {
      atomicAdd(&statsOut[brow0 + tid], smS[tid] + smS[128 + tid]);
      atomicAdd(&statsOut[256 + brow0 + tid], smQ[tid] + smQ[128 + tid]);
    }
  }

  const int rbase = (int)arow0 + wr * 64 + (lane >> 4) * 4;
  const int cbase = (int)brow0 + wc * 64 + (lane & 15);
#pragma unroll
  for (int m = 0; m < 4; ++m) {
#pragma unroll
    for (int n = 0; n < 4; ++n) {
      int col = cbase + n * 16;
      if (col >= Nvalid) continue;
      float badd = bias ? bias[col] : 0.f;
#pragma unroll
      for (int r = 0; r < 4; ++r) {
        int row = rbase + m * 16 + r;
        if (row < Mvalid) {
          if constexpr (BF16OUT)
            ((bf16*)Cout)[(size_t)row * ldc + col] = __float2bfloat16(acc[m][n][r] + badd);
          else
            ((float*)Cout)[(size_t)row * ldc + col] = acc[m][n][r] + badd;
        }
      }
    }
  }
}

// ---------------- GAT pieces (h is bf16) ----------------

__global__ __launch_bounds__(256) void att_reduce(
    const bf16* __restrict__ h, const float* __restrict__ ats, const float* __restrict__ atd,
    float* __restrict__ a_s, float* __restrict__ a_d) {
  int n = blockIdx.x;
  int lane = threadIdx.x & 63;
  int hd = threadIdx.x >> 6;
  const bf16* hp = h + (size_t)n * 512 + hd * 128;
  const float* sw = ats + hd * 128;
  const float* dw = atd + hd * 128;
  float h1 = __bfloat162float(hp[lane]), h2 = __bfloat162float(hp[lane + 64]);
  float s = h1 * sw[lane] + h2 * sw[lane + 64];
  float d = h1 * dw[lane] + h2 * dw[lane + 64];
#pragma unroll
  for (int off = 32; off > 0; off >>= 1) {
    s += __shfl_down(s, off);
    d += __shfl_down(d, off);
  }
  if (lane == 0) {
    a_s[n * 4 + hd] = s;
    a_d[n * 4 + hd] = d;
  }
}

__global__ void edge_alpha_max(const int* __restrict__ ei, const float* __restrict__ a_s,
                               const float* __restrict__ a_d, float* __restrict__ alphaE,
                               u32* __restrict__ amaxU) {
  int t = blockIdx.x * 256 + threadIdx.x;
  if (t >= NEDGES * 4) return;
  int e = t >> 2, h = t & 3;
  int s = ei[e], d = ei[NEDGES + e];
  float a = a_s[s * 4 + h] + a_d[d * 4 + h];
  a = (a > 0.f) ? a : NEG_SLOPE * a;
  alphaE[t] = a;
  u32 bits = __float_as_uint(a);
  u32 key = bits ^ (((int)bits < 0) ? 0xFFFFFFFFu : 0x80000000u);
  atomicMax(&amaxU[d * 4 + h], key);
}

__global__ void edge_exp_sum(const int* __restrict__ ei, float* __restrict__ alphaE,
                             const u32* __restrict__ amaxU, float* __restrict__ denom) {
  int t = blockIdx.x * 256 + threadIdx.x;
  if (t >= NEDGES * 4) return;
  int e = t >> 2, h = t & 3;
  int d = ei[NEDGES + e];
  u32 k = amaxU[d * 4 + h];
  u32 bits = (k & 0x80000000u) ? (k ^ 0x80000000u) : ~k;
  float am = __uint_as_float(bits);
  float ev = __expf(alphaE[t] - am);
  alphaE[t] = ev;
  atomicAdd(&denom[d * 4 + h], ev);
}

__global__ void edge_scatter(const int* __restrict__ ei, const bf16* __restrict__ hbuf,
                             const float* __restrict__ evals, const float* __restrict__ denom,
                             float* __restrict__ agg) {
  int e = blockIdx.x * 2 + (threadIdx.x >> 7);
  int d = threadIdx.x & 127;
  int s = ei[e], dd = ei[NEDGES + e];
  const short* hp = (const short*)hbuf + (size_t)s * 512 + d;
  float sum = 0.f;
#pragma unroll
  for (int h = 0; h < 4; ++h) {
    float coef = evals[e * 4 + h] / denom[dd * 4 + h];
    sum += b2f(hp[h * 128]) * coef;
  }
  atomicAdd(&agg[dd * 128 + d], sum * 0.25f);
}

// ---------------- BatchNorm pieces ----------------

__global__ __launch_bounds__(256) void col_stats128(const float* __restrict__ X,
                                                    float* __restrict__ stats, int rows) {
  __shared__ float smS[8][128], smQ[8][128];
  int t = threadIdx.x;
  int sub = t >> 5;
  int c4 = (t & 31) * 4;
  int rend = blockIdx.x * 64 + 64;
  if (rend > rows) rend = rows;
  f32x4 s = {}, q = {};
  for (int r = blockIdx.x * 64 + sub; r < rend; r += 8) {
    f32x4 v = *(const f32x4*)&X[(size_t)r * 128 + c4];
    s += v;
    q += v * v;
  }
  *(f32x4*)&smS[sub][c4] = s;
  *(f32x4*)&smQ[sub][c4] = q;
  __syncthreads();
  if (t < 128) {
    float ts = 0.f, tq = 0.f;
#pragma unroll
    for (int g = 0; g < 8; ++g) { ts += smS[g][t]; tq += smQ[g][t]; }
    atomicAdd(&stats[t], ts);
    atomicAdd(&stats[128 + t], tq);
  }
}

__global__ void bn_relu_node(const float* __restrict__ agg, const float* __restrict__ stats,
                             const float* __restrict__ w, const float* __restrict__ b,
                             bf16* __restrict__ xout) {
  int i = blockIdx.x * 256 + threadIdx.x;
  if (i >= NODE_PAD * 128) return;
  int r = i >> 7, c = i & 127;
  float v = 0.f;
  if (r < NNODES) {
    float m = stats[c] * (1.f / NNODES);
    float var = stats[128 + c] * (1.f / NNODES) - m * m;
    float rstd = rsqrtf(var + BN_EPS);
    v = fmaxf((agg[i] - m) * rstd * w[c] + b[c], 0.f);
  }
  xout[i] = __float2bfloat16(v);
}

__global__ void bn_res_relu_node(const float* __restrict__ agg, const float* __restrict__ stats,
                                 const float* __restrict__ w, const float* __restrict__ b,
                                 const bf16* __restrict__ x1b, bf16* __restrict__ xrb) {
  int i = blockIdx.x * 256 + threadIdx.x;
  if (i >= NODE_PAD * 128) return;
  int r = i >> 7, c = i & 127;
  float v = 0.f;
  if (r < NNODES) {
    float m = stats[c] * (1.f / NNODES);
    float var = stats[128 + c] * (1.f / NNODES) - m * m;
    float rstd = rsqrtf(var + BN_EPS);
    v = fmaxf((agg[i] - m) * rstd * w[c] + b[c] + __bfloat162float(x1b[i]), 0.f);
  }
  xrb[i] = __float2bfloat16(v);
}

// ---------------- edge-MLP head ----------------
// Pass 1: gather y1 = P[src]+Q[dst] ONCE (PQ bf16); write y1 bf16 + col stats.
__device__ __forceinline__ void accum_edge(short8 pa, short8 qa, bf16* __restrict__ y1out,
                                           size_t obase, f32x4& s0, f32x4& s1,
                                           f32x4& q0, f32x4& q1) {
  short8 o;
  float v[8];
#pragma unroll
  for (int j = 0; j < 8; ++j) {
    v[j] = b2f(pa[j]) + b2f(qa[j]);
    o[j] = f2b(v[j]);
  }
  *(short8*)(y1out + obase) = o;
  s0[0] += v[0]; s0[1] += v[1]; s0[2] += v[2]; s0[3] += v[3];
  s1[0] += v[4]; s1[1] += v[5]; s1[2] += v[6]; s1[3] += v[7];
  q0[0] += v[0] * v[0]; q0[1] += v[1] * v[1]; q0[2] += v[2] * v[2]; q0[3] += v[3] * v[3];
  q1[0] += v[4] * v[4]; q1[1] += v[5] * v[5]; q1[2] += v[6] * v[6]; q1[3] += v[7] * v[7];
}

__global__ __launch_bounds__(256) void e_stats_mat(const int* __restrict__ ei,
                                                   const bf16* __restrict__ PQ,
                                                   bf16* __restrict__ y1out,
                                                   float* __restrict__ stats) {
  __shared__ float smS[8][256], smQ[8][256];
  int t = threadIdx.x;
  int sub = t >> 5;
  int c8 = (t & 31) * 8;
  int ebase = blockIdx.x * 128 + sub * 16;
  f32x4 s0 = {}, s1 = {}, q0 = {}, q1 = {};
#pragma unroll 1
  for (int i = 0; i < 16; i += 4) {
    int e = ebase + i;
    if (e + 3 < NEDGES) {
      int4 sn = *(const int4*)&ei[e];
      int4 dn = *(const int4*)&ei[NEDGES + e];
      short8 p0 = *(const short8*)&PQ[(size_t)sn.x * 512 + c8];
      short8 p1 = *(const short8*)&PQ[(size_t)sn.y * 512 + c8];
      short8 p2 = *(const short8*)&PQ[(size_t)sn.z * 512 + c8];
      short8 p3 = *(const short8*)&PQ[(size_t)sn.w * 512 + c8];
      short8 r0 = *(const short8*)&PQ[(size_t)dn.x * 512 + 256 + c8];
      short8 r1 = *(const short8*)&PQ[(size_t)dn.y * 512 + 256 + c8];
      short8 r2 = *(const short8*)&PQ[(size_t)dn.z * 512 + 256 + c8];
      short8 r3 = *(const short8*)&PQ[(size_t)dn.w * 512 + 256 + c8];
      accum_edge(p0, r0, y1out, (size_t)e * 256 + c8, s0, s1, q0, q1);
      accum_edge(p1, r1, y1out, (size_t)(e + 1) * 256 + c8, s0, s1, q0, q1);
      accum_edge(p2, r2, y1out, (size_t)(e + 2) * 256 + c8, s0, s1, q0, q1);
      accum_edge(p3, r3, y1out, (size_t)(e + 3) * 256 + c8, s0, s1, q0, q1);
    } else {
      for (int j = 0; j < 4; ++j) {
        int ej = e + j;
        if (ej >= NEDGES) break;
        int sn = ei[ej], dn = ei[NEDGES + ej];
        short8 p = *(const short8*)&PQ[(size_t)sn * 512 + c8];
        short8 r = *(const short8*)&PQ[(size_t)dn * 512 + 256 + c8];
        accum_edge(p, r, y1out, (size_t)ej * 256 + c8, s0, s1, q0, q1);
      }
    }
  }
  *(f32x4*)&smS[sub][c8] = s0;
  *(f32x4*)&smS[sub][c8 + 4] = s1;
  *(f32x4*)&smQ[sub][c8] = q0;
  *(f32x4*)&smQ[sub][c8 + 4] = q1;
  __syncthreads();
  float ts = 0.f, tq = 0.f;
#pragma unroll
  for (int g = 0; g < 8; ++g) { ts += smS[g][t]; tq += smQ[g][t]; }
  atomicAdd(&stats[t], ts);
  atomicAdd(&stats[256 + t], tq);
}

// Pass 2: ef2 = relu(bn3(y1) + xr[src|dst]) IN PLACE on the y1 buffer.
__global__ __launch_bounds__(256) void ef2_norm(const int* __restrict__ ei,
                                                const bf16* __restrict__ xrb,
                                                const float* __restrict__ stats,
                                                const float* __restrict__ w,
                                                const float* __restrict__ b,
                                                bf16* __restrict__ ef2) {
  int t = threadIdx.x;
  int e = blockIdx.x * 8 + (t >> 5);
  int c8 = (t & 31) * 8;
  size_t base = (size_t)e * 256 + c8;
  short8 out = {};
  if (e < NEDGES) {
    int node = (c8 < 128) ? ei[e] : ei[NEDGES + e];
    short8 yv = *(const short8*)&ef2[base];
    short8 res = *(const short8*)&xrb[(size_t)node * 128 + (c8 & 127)];
#pragma unroll
    for (int j = 0; j < 8; ++j) {
      int c = c8 + j;
      float m = stats[c] * (1.f / NEDGES);
      float var = stats[256 + c] * (1.f / NEDGES) - m * m;
      float rstd = rsqrtf(var + BN_EPS);
      float v = (b2f(yv[j]) - m) * rstd * w[c] + b[c] + b2f(res[j]);
      out[j] = f2b(fmaxf(v, 0.f));
    }
  }
  *(short8*)&ef2[base] = out;
}

// ---------------- launch ----------------

extern "C" void kernel_launch(void* const* d_in, const int* in_sizes, int n_in,
                              void* d_out, int out_size, void* d_ws, size_t ws_size,
                              hipStream_t stream) {
  const float* x    = (const float*)d_in[0];
  const int*   ei   = (const int*)d_in[1];
  const float* w0   = (const float*)d_in[2];
  const float* ats0 = (const float*)d_in[4];
  const float* atd0 = (const float*)d_in[5];
  const float* bn1w = (const float*)d_in[6];
  const float* bn1b = (const float*)d_in[7];
  const float* w2   = (const float*)d_in[8];
  const float* ats1 = (const float*)d_in[10];
  const float* atd1 = (const float*)d_in[11];
  const float* bn2w = (const float*)d_in[12];
  const float* bn2b = (const float*)d_in[13];
  const float* w4   = (const float*)d_in[14];
  const float* bn3w = (const float*)d_in[16];
  const float* bn3b = (const float*)d_in[17];
  const float* w6   = (const float*)d_in[18];
  const float* bn4w = (const float*)d_in[20];
  const float* bn4b = (const float*)d_in[21];
  const float* w8   = (const float*)d_in[22];
  const float* b8   = (const float*)d_in[23];

  // ---- explicit workspace layout (peak ~307.8 MB) ----
  const size_t REG = 153616384;  // EDGE_PAD*256*2
  char* ws = (char*)d_ws;
  bf16*  ef2b = (bf16*)ws;          // y1 -> ef2 (in place) -> residual for fused GEMM3
  char*  R    = ws + REG;
  bf16*  hb    = (bf16*)(R);                  // node GEMM out (bf16) / later PQ
  bf16*  xb    = (bf16*)(R + 61603840);
  bf16*  x1b   = (bf16*)(R + 65454080);
  bf16*  xrb   = (bf16*)(R + 73154560);
  float* a_s   = (float*)(R + 80855040);
  float* a_d   = (float*)(R + 81335040);
  u32*   amaxU = (u32*)  (R + 81815040);
  float* denom = (float*)(R + 82295040);
  float* alphaE= (float*)(R + 82775040);
  float* agg   = (float*)(R + 87575040);
  bf16*  PQ    = hb;
  bf16*  y2b   = (bf16*)R;                    // GEMM2 out, overwrites node stuff
  char*  S     = ws + 2 * REG;
  bf16*  w0b   = (bf16*)(S);
  bf16*  w2b   = (bf16*)(S + 65536);
  bf16*  w45b  = (bf16*)(S + 196608);
  bf16*  w6b   = (bf16*)(S + 327680);
  bf16*  w8pb  = (bf16*)(S + 458752);
  float* stats1= (float*)(S + 524288);
  float* stats2= (float*)(S + 526336);
  float* sc2   = (float*)(S + 528384);
  float* sh2   = (float*)(S + 529408);
  const size_t needed = 2 * REG + 530432;
  if (ws_size < needed) {
    fillpat<<<(out_size + 255) / 256, 256, 0, stream>>>((u32*)d_out, 0x7F7F7F7Fu, out_size);
    return;
  }

  // ---- convert inputs/weights to bf16 (padded) ----
  cvt_bf16_pad<<<(NODE_PAD * 64 + 255) / 256, 256, 0, stream>>>(x, xb, NNODES, NODE_PAD * 64, 64);
  cvt_bf16_pad<<<(512 * 64 + 255) / 256, 256, 0, stream>>>(w0, w0b, 512, 512 * 64, 64);
  cvt_bf16_pad<<<(512 * 128 + 255) / 256, 256, 0, stream>>>(w2, w2b, 512, 512 * 128, 128);
  cvt_w45<<<(512 * 128 + 255) / 256, 256, 0, stream>>>(w4, w45b);
  cvt_bf16_pad<<<(256 * 256 + 255) / 256, 256, 0, stream>>>(w6, w6b, 256, 256 * 256, 256);
  cvt_bf16_pad<<<(128 * 256 + 255) / 256, 256, 0, stream>>>(w8, w8pb, 86, 128 * 256, 256);

  const int etb = (NEDGES * 4 + 255) / 256;

  // ---- GAT layer 1 ----
  gemm_bt<true, false, false><<<dim3(NODE_PAD / 128, 4), 256, 0, stream>>>(
      xb, w0b, hb, 64, 512, NODE_PAD, 512, nullptr, nullptr, nullptr, nullptr, nullptr);
  att_reduce<<<NNODES, 256, 0, stream>>>(hb, ats0, atd0, a_s, a_d);
  zfill<<<(240000 + 255) / 256, 256, 0, stream>>>(amaxU, 240000);
  zfill<<<(3840000 + 255) / 256, 256, 0, stream>>>((u32*)agg, 3840000);
  edge_alpha_max<<<etb, 256, 0, stream>>>(ei, a_s, a_d, alphaE, amaxU);
  edge_exp_sum<<<etb, 256, 0, stream>>>(ei, alphaE, amaxU, denom);
  edge_scatter<<<NEDGES / 2, 256, 0, stream>>>(ei, hb, alphaE, denom, agg);
  zfill<<<1, 256, 0, stream>>>((u32*)stats1, 256);
  col_stats128<<<(NNODES + 63) / 64, 256, 0, stream>>>(agg, stats1, NNODES);
  bn_relu_node<<<NODE_PAD * 128 / 256, 256, 0, stream>>>(agg, stats1, bn1w, bn1b, x1b);

  // ---- GAT layer 2 ----
  gemm_bt<true, false, false><<<dim3(NODE_PAD / 128, 4), 256, 0, stream>>>(
      x1b, w2b, hb, 128, 512, NODE_PAD, 512, nullptr, nullptr, nullptr, nullptr, nullptr);
  att_reduce<<<NNODES, 256, 0, stream>>>(hb, ats1, atd1, a_s, a_d);
  zfill<<<(240000 + 255) / 256, 256, 0, stream>>>(amaxU, 240000);
  zfill<<<(3840000 + 255) / 256, 256, 0, stream>>>((u32*)agg, 3840000);
  edge_alpha_max<<<etb, 256, 0, stream>>>(ei, a_s, a_d, alphaE, amaxU);
  edge_exp_sum<<<etb, 256, 0, stream>>>(ei, alphaE, amaxU, denom);
  edge_scatter<<<NEDGES / 2, 256, 0, stream>>>(ei, hb, alphaE, denom, agg);
  zfill<<<1, 256, 0, stream>>>((u32*)stats1, 256);
  col_stats128<<<(NNODES + 63) / 64, 256, 0, stream>>>(agg, stats1, NNODES);
  bn_res_relu_node<<<NODE_PAD * 128 / 256, 256, 0, stream>>>(agg, stats1, bn2w, bn2b, x1b, xrb);

  // ---- edge MLP ----
  gemm_bt<true, false, false><<<dim3(NODE_PAD / 128, 4), 256, 0, stream>>>(
      xrb, w45b, PQ, 128, 512, NODE_PAD, 512, nullptr, nullptr, nullptr, nullptr, nullptr);
  zfill<<<2, 256, 0, stream>>>((u32*)stats1, 512);
  e_stats_mat<<<(NEDGES + 127) / 128, 256, 0, stream>>>(ei, PQ, ef2b, stats1);
  ef2_norm<<<EDGE_PAD / 8, 256, 0, stream>>>(ei, xrb, stats1, bn3w, bn3b, ef2b);
  zfill<<<2, 256, 0, stream>>>((u32*)stats2, 512);
  gemm_bt<true, true, false><<<dim3(EDGE_PAD / 128, 2), 256, 0, stream>>>(
      ef2b, w6b, y2b, 256, 256, EDGE_PAD, 256, nullptr, stats2, nullptr, nullptr, nullptr);
  bn_coef<<<1, 256, 0, stream>>>(stats2, bn4w, bn4b, 256, 1.f / NEDGES, sc2, sh2);
  // GEMM3 with fused ef3 = relu(bn4(y2) + ef2) on the A-staging path
  gemm_bt<false, false, true><<<dim3(EDGE_PAD / 128, 1), 256, 0, stream>>>(
      y2b, w8pb, (float*)d_out, 256, 86, NEDGES, 86, b8, nullptr, ef2b, sc2, sh2);
}